// Round 11
// baseline (208.907 us; speedup 1.0000x reference)
//
#include <hip/hip_runtime.h>

#define S_ 2304   // 48*48

typedef unsigned short u16;
typedef __attribute__((ext_vector_type(8))) short bf16x8;
typedef __attribute__((ext_vector_type(4))) float f32x4;

static __device__ __forceinline__ u16 f2bf(float x) {
  union { float f; unsigned u; } v; v.f = x;
  unsigned r = v.u + 0x7FFFu + ((v.u >> 16) & 1u);
  return (u16)(r >> 16);
}
static __device__ __forceinline__ float bf2f(u16 h) {
  union { unsigned u; float f; } v; v.u = ((unsigned)h) << 16; return v.f;
}

// ---------------------------------------------------------------------------
// Weight split (both weight tensors in one dispatch):
// blocks 0..191 -> rcv_w (768x256), blocks 192..255 -> proj_w (256x256).
// ---------------------------------------------------------------------------
__global__ __launch_bounds__(256) void splitw_kernel(
    const float* __restrict__ w0, u16* __restrict__ wh0, u16* __restrict__ wl0,
    const float* __restrict__ w1, u16* __restrict__ wh1, u16* __restrict__ wl1)
{
  const float* w; u16 *wh, *wl; int id;
  if (blockIdx.x < 192) { w = w0; wh = wh0; wl = wl0; id = blockIdx.x * 256 + threadIdx.x; }
  else { w = w1; wh = wh1; wl = wl1; id = (blockIdx.x - 192) * 256 + threadIdx.x; }
  float4 v = ((const float4*)w)[id];
  short4 h, l;
  float f[4] = {v.x, v.y, v.z, v.w};
  u16 hh[4], ll[4];
#pragma unroll
  for (int q = 0; q < 4; q++) {
    hh[q] = f2bf(f[q]);
    ll[q] = f2bf(f[q] - bf2f(hh[q]));
  }
  h.x = hh[0]; h.y = hh[1]; h.z = hh[2]; h.w = hh[3];
  l.x = ll[0]; l.y = ll[1]; l.z = ll[2]; l.w = ll[3];
  ((short4*)wh)[id] = h;
  ((short4*)wl)[id] = l;
}

// ---------------------------------------------------------------------------
// MFMA split-bf16 GEMM, B staged DIRECTLY from fp32 [k][s] source (fused
// split-transpose): per kstep, stage 32k x 128s tile -> LDS [col][k pad 40]
// bf16 h (and l if XLO), double-buffered, 1 barrier/kstep.
// XLO=false: Out = (Wh+Wl)*Xh  (2 MFMA/mt/nt)   [x path]
// XLO=true : Out = Wh*Xh+Wh*Xl+Wl*Xh (3 MFMA)   [y->proj path]
// ---------------------------------------------------------------------------
template <bool XLO>
__global__ __launch_bounds__(256) void gemm_mfma_kernel(
    const u16* __restrict__ Wh, const u16* __restrict__ Wl,
    const float* __restrict__ bias,
    const float* __restrict__ Xf,     // [b][256][S_] fp32
    float* __restrict__ Out, int M)
{
  __shared__ u16 wAh[2][64 * 40];            // 5120 B per buf
  __shared__ u16 wAl[2][64 * 40];
  __shared__ u16 xBh[2][128 * 40];           // 10240 B per buf
  __shared__ u16 xBl[XLO ? 2 : 1][128 * 40]; // only used when XLO
  const int MB = M >> 6;
  const int xcd = blockIdx.x & 7;
  const int idx = blockIdx.x >> 3;          // 0 .. 9*MB-1
  const int g = xcd * 9 + idx / MB;         // 0..71 group = (n_blk, b)
  const int mb = idx % MB;
  const int nb = g % 18, b = g / 18;
  const int m0 = mb * 64, n0 = nb * 128;
  const int tid = threadIdx.x;
  const int wv = tid >> 6, lane = tid & 63;
  const int lr = lane & 15, lg = lane >> 4;

  const float* Xb = Xf + (size_t)b * 256 * S_ + n0;   // [k][s], col offset n0

  f32x4 acc[4][2];
#pragma unroll
  for (int mt = 0; mt < 4; mt++)
#pragma unroll
    for (int nt = 0; nt < 2; nt++) acc[mt][nt] = (f32x4){0.f, 0.f, 0.f, 0.f};

#define STAGE_W(t, buf)                                                      \
  {                                                                          \
    _Pragma("unroll")                                                        \
    for (int r = 0; r < 2; r++) {                                            \
      int id = tid + r * 256;                                                \
      int m = id >> 3, k4 = (id & 7) * 4;                                    \
      *(short4*)&wAh[buf][m * 40 + k4] =                                     \
          *(const short4*)&Wh[(size_t)(m0 + m) * 256 + (t) * 32 + k4];       \
      *(short4*)&wAl[buf][m * 40 + k4] =                                     \
          *(const short4*)&Wl[(size_t)(m0 + m) * 256 + (t) * 32 + k4];       \
    }                                                                        \
  }

#define STAGE_B(t, buf)                                                      \
  {                                                                          \
    _Pragma("unroll")                                                        \
    for (int p = 0; p < 4; p++) {                                            \
      int row = p * 8 + (tid >> 5);         /* k 0..31 */                    \
      int col4 = (tid & 31) * 4;            /* s 0..127 */                   \
      float4 v = *(const float4*)&Xb[(size_t)((t) * 32 + row) * S_ + col4];  \
      float f[4] = {v.x, v.y, v.z, v.w};                                    \
      _Pragma("unroll")                                                      \
      for (int q = 0; q < 4; q++) {                                          \
        u16 h = f2bf(f[q]);                                                  \
        xBh[buf][(col4 + q) * 40 + row] = h;                                 \
        if (XLO)                                                             \
          xBl[buf][(col4 + q) * 40 + row] = f2bf(f[q] - bf2f(h));            \
      }                                                                      \
    }                                                                        \
  }

  STAGE_W(0, 0);
  STAGE_B(0, 0);
  __syncthreads();

  for (int t = 0; t < 8; t++) {
    int buf = t & 1;
    if (t < 7) { STAGE_W(t + 1, buf ^ 1); STAGE_B(t + 1, buf ^ 1); }

    // A fragments from LDS
    bf16x8 ah[4], al[4];
#pragma unroll
    for (int mt = 0; mt < 4; mt++) {
      ah[mt] = *(const bf16x8*)&wAh[buf][(mt * 16 + lr) * 40 + lg * 8];
      al[mt] = *(const bf16x8*)&wAl[buf][(mt * 16 + lr) * 40 + lg * 8];
    }
    // B fragments from LDS
    bf16x8 bh[2], bl[2];
#pragma unroll
    for (int nt = 0; nt < 2; nt++) {
      bh[nt] = *(const bf16x8*)&xBh[buf][(wv * 32 + nt * 16 + lr) * 40 + lg * 8];
      if (XLO)
        bl[nt] = *(const bf16x8*)&xBl[buf][(wv * 32 + nt * 16 + lr) * 40 + lg * 8];
    }
#pragma unroll
    for (int mt = 0; mt < 4; mt++)
#pragma unroll
      for (int nt = 0; nt < 2; nt++) {
        acc[mt][nt] = __builtin_amdgcn_mfma_f32_16x16x32_bf16(ah[mt], bh[nt], acc[mt][nt], 0, 0, 0);
        if (XLO)
          acc[mt][nt] = __builtin_amdgcn_mfma_f32_16x16x32_bf16(ah[mt], bl[nt], acc[mt][nt], 0, 0, 0);
        acc[mt][nt] = __builtin_amdgcn_mfma_f32_16x16x32_bf16(al[mt], bh[nt], acc[mt][nt], 0, 0, 0);
      }
    __syncthreads();
  }

  // epilogue: D col = lane&15 (s), row = lg*4+reg (m)
  float* ob = Out + (size_t)b * M * S_;
#pragma unroll
  for (int mt = 0; mt < 4; mt++) {
    float4 b4 = *(const float4*)&bias[m0 + mt * 16 + lg * 4];
    float bv[4] = {b4.x, b4.y, b4.z, b4.w};
#pragma unroll
    for (int nt = 0; nt < 2; nt++) {
      int s = n0 + wv * 32 + nt * 16 + lr;
#pragma unroll
      for (int r = 0; r < 4; r++) {
        int m = m0 + mt * 16 + lg * 4 + r;
        ob[(size_t)m * S_ + s] = acc[mt][nt][r] + bv[r];
      }
    }
  }
#undef STAGE_W
#undef STAGE_B
}

// ---------------------------------------------------------------------------
// Row attention -> arF fragment-major (r10), wave-parallel softmax.
// ---------------------------------------------------------------------------
__global__ __launch_bounds__(256) void row_attn_kernel(
    const float* __restrict__ rcv, u16* __restrict__ arF)
{
  __shared__ u16  rq[16 * 2304];     // [d][i*48+w]  73728 B
  __shared__ float rk[16 * 48];
  __shared__ float Sm[48 * 49];      // [i][w] padded
  __shared__ float cmax[48], crs[48];
  const int hg = blockIdx.x, n = blockIdx.y, b = blockIdx.z;
  const float* base = rcv + ((size_t)b * 768 + n * 96) * S_;  // rq; rk at +16*S_
  const int tid = threadIdx.x;

  for (int id = tid; id < 9216; id += 256) {     // 16*2304/4 float4s
    float4 v = *(const float4*)&base[id * 4];
    short4 s;
    s.x = (short)f2bf(v.x); s.y = (short)f2bf(v.y);
    s.z = (short)f2bf(v.z); s.w = (short)f2bf(v.w);
    *(short4*)&rq[id * 4] = s;
  }

  for (int hh = 0; hh < 6; hh++) {
    int h = hg * 6 + hh;
    for (int id = tid; id < 768; id += 256) {
      int d = id / 48, w = id % 48;
      rk[id] = base[(size_t)(16 + d) * S_ + h * 48 + w];
    }
    __syncthreads();
    for (int id = tid; id < 2304; id += 256) {
      int i = id / 48, w = id % 48;
      float s = 0.f;
#pragma unroll
      for (int d = 0; d < 16; d++)
        s += bf2f(rq[d * 2304 + i * 48 + w]) * rk[d * 48 + w];
      Sm[i * 49 + w] = s * 0.25f;
    }
    __syncthreads();
    if (tid < 192) {
      int w = tid >> 2, e = tid & 3;
      float m = -1e30f;
      for (int i = e; i < 48; i += 4) m = fmaxf(m, Sm[i * 49 + w]);
      m = fmaxf(m, __shfl_xor(m, 1));
      m = fmaxf(m, __shfl_xor(m, 2));
      float s = 0.f;
      for (int i = e; i < 48; i += 4) s += __expf(Sm[i * 49 + w] - m);
      s += __shfl_xor(s, 1);
      s += __shfl_xor(s, 2);
      cmax[w] = m; crs[w] = 1.0f / s;
    }
    __syncthreads();
    u16* dst = arF + ((size_t)(b * 8 + n) * 48 + h) * 2304;
    for (int id = tid; id < 576; id += 256) {   // one 8B fragment chunk each
      int nt = id / 192, rem = id % 192, mt = rem / 64, l = rem % 64;
      int w = nt * 16 + (l & 15);
      int i0 = mt * 16 + ((l >> 4) << 2);
      short4 o;
      o.x = (short)f2bf(__expf(Sm[(i0 + 0) * 49 + w] - cmax[w]) * crs[w]);
      o.y = (short)f2bf(__expf(Sm[(i0 + 1) * 49 + w] - cmax[w]) * crs[w]);
      o.z = (short)f2bf(__expf(Sm[(i0 + 2) * 49 + w] - cmax[w]) * crs[w]);
      o.w = (short)f2bf(__expf(Sm[(i0 + 3) * 49 + w] - cmax[w]) * crs[w]);
      *(short4*)&dst[id * 4] = o;   // coalesced
    }
    __syncthreads();
  }
}

// ---------------------------------------------------------------------------
// Col attention -> awF fragment-major (r10), wave-parallel softmax.
// ---------------------------------------------------------------------------
__global__ __launch_bounds__(256) void col_attn_kernel(
    const float* __restrict__ rcv, u16* __restrict__ awF)
{
  __shared__ float cq[16 * 48], ck[16 * 48];
  __shared__ float Tm[48 * 49];
  __shared__ float rmax[48], rrs[48];
  const int hg = blockIdx.x, n = blockIdx.y, b = blockIdx.z;
  const float* base = rcv + ((size_t)b * 768 + n * 96 + 32) * S_; // cq; ck at +16*S_
  const int tid = threadIdx.x;

  for (int hh = 0; hh < 6; hh++) {
    int h = hg * 6 + hh;
    for (int id = tid; id < 768; id += 256) {
      int d = id / 48, j = id % 48;
      cq[id] = base[(size_t)d * S_ + h * 48 + j];
      ck[id] = base[(size_t)(16 + d) * S_ + h * 48 + j];
    }
    __syncthreads();
    for (int id = tid; id < 2304; id += 256) {
      int w = id / 48, j = id % 48;
      float t = 0.f;
#pragma unroll
      for (int d = 0; d < 16; d++)
        t += ck[d * 48 + w] * cq[d * 48 + j];
      Tm[w * 49 + j] = t * 0.25f;
    }
    __syncthreads();
    if (tid < 192) {
      int w = tid >> 2, e = tid & 3;
      float m = -1e30f;
      for (int j = e; j < 48; j += 4) m = fmaxf(m, Tm[w * 49 + j]);
      m = fmaxf(m, __shfl_xor(m, 1));
      m = fmaxf(m, __shfl_xor(m, 2));
      float s = 0.f;
      for (int j = e; j < 48; j += 4) s += __expf(Tm[w * 49 + j] - m);
      s += __shfl_xor(s, 1);
      s += __shfl_xor(s, 2);
      rmax[w] = m; rrs[w] = 1.0f / s;
    }
    __syncthreads();
    u16* dst = awF + ((size_t)(b * 8 + n) * 48 + h) * 3072;
    for (int id = tid; id < 384; id += 256) {   // one 16B fragment chunk each
      int nt = id / 128, rem = id % 128, ks = rem / 64, l = rem % 64;
      int w = nt * 16 + (l & 15);
      int j0 = ks * 32 + ((l >> 4) << 3);
      u16 t8[8];
#pragma unroll
      for (int e = 0; e < 8; e++) {
        int j = j0 + e;
        t8[e] = (j < 48) ? f2bf(__expf(Tm[w * 49 + j] - rmax[w]) * rrs[w]) : (u16)0;
      }
      short4 o0, o1;
      o0.x = (short)t8[0]; o0.y = (short)t8[1]; o0.z = (short)t8[2]; o0.w = (short)t8[3];
      o1.x = (short)t8[4]; o1.y = (short)t8[5]; o1.z = (short)t8[6]; o1.w = (short)t8[7];
      *(short4*)&dst[id * 8]     = o0;
      *(short4*)&dst[id * 8 + 4] = o1;
    }
    __syncthreads();
  }
}

// ---------------------------------------------------------------------------
// Main contraction + PE conv. 4 v-planes per block (vA 27.6 KB), wave=plane,
// 12 h per wave -> all 4 waves stream IDENTICAL aw/ar fragments (L1 reuse;
// halves L2 traffic vs r10's 2-plane shape). Fragment-major coalesced loads.
// Grid 1024 blocks (1-D, XCD swizzle) = 4 blocks/CU resident, 16 waves/CU.
// ---------------------------------------------------------------------------
__global__ __launch_bounds__(256) void attn_main_kernel(
    const float* __restrict__ rcv, const u16* __restrict__ arF,
    const u16* __restrict__ awF, const float* __restrict__ pe_w,
    const float* __restrict__ pe_b, float* __restrict__ y)
{
  __shared__ u16 vA[192 * 72];        // 27648 B  [(dloc,i)][j pad]
  const int id0 = blockIdx.x;
  const int n = id0 & 7;              // XCD swizzle
  const int rest = id0 >> 3;          // 0..127
  const int b = rest >> 5;            // 0..3
  const int inner = rest & 31;        // 0..31
  const int dchunk = inner >> 2;      // 0..7 (4 planes each)
  const int hc = inner & 3;           // 0..3
  const int h0 = hc * 12;
  const int tid = threadIdx.x;
  const int wave = tid >> 6, lane = tid & 63;
  const int lr = lane & 15, lg = lane >> 4;

  // zero only the j-pad columns (48..71); staging fills cols 0..47
  for (int id = tid; id < 192 * 24; id += 256) {
    int row = id / 24, col = 48 + id % 24;
    vA[row * 72 + col] = 0;
  }
  const float* vbase = rcv + ((size_t)b * 768 + n * 96 + 64 + dchunk * 4) * S_;
  for (int id = tid; id < 2304; id += 256) {   // 4 planes * 576 float4
    int dl2 = id / 576, rem = id % 576;
    int i = rem / 12, j4 = (rem % 12) * 4;
    float4 v = *(const float4*)&vbase[(size_t)dl2 * S_ + i * 48 + j4];
    short4 s;
    s.x = (short)f2bf(v.x); s.y = (short)f2bf(v.y);
    s.z = (short)f2bf(v.z); s.w = (short)f2bf(v.w);
    *(short4*)&vA[(dl2 * 48 + i) * 72 + j4] = s;
  }
  __syncthreads();   // the only barrier

  const size_t bn48 = (size_t)(b * 8 + n) * 48;
  const int c = n * 32 + dchunk * 4 + wave;   // global channel of this wave's d-plane
  float pw[9];
#pragma unroll
  for (int t = 0; t < 9; t++) pw[t] = pe_w[c * 9 + t];
  const float pb = pe_b[c];
  float* yg = y + ((size_t)b * 256 + c) * S_;
  const int vrow0 = wave * 48;

  for (int hh = 0; hh < 12; hh++) {
    int h = h0 + hh;
    const u16* awg = awF + (bn48 + h) * 3072;  // fragment-major
    const u16* arg = arF + (bn48 + h) * 2304;  // fragment-major

    // B fragments: lane-consecutive 16B loads (coalesced, shared by 4 waves)
    bf16x8 bf0[3], bf1[3];
#pragma unroll
    for (int nt = 0; nt < 3; nt++) {
      bf0[nt] = *(const bf16x8*)&awg[nt * 1024 + lane * 8];        // ks=0: j 0..31
      bf1[nt] = *(const bf16x8*)&awg[nt * 1024 + 512 + lane * 8];  // ks=1: j 32..47|0
    }

    f32x4 acc[3][3];
#pragma unroll
    for (int mt = 0; mt < 3; mt++)
#pragma unroll
      for (int nt = 0; nt < 3; nt++) acc[mt][nt] = (f32x4){0.f, 0.f, 0.f, 0.f};

#pragma unroll
    for (int mt = 0; mt < 3; mt++) {
      bf16x8 a0 = *(const bf16x8*)&vA[(vrow0 + mt * 16 + lr) * 72 + lg * 8];
      bf16x8 a1 = *(const bf16x8*)&vA[(vrow0 + mt * 16 + lr) * 72 + 32 + lg * 8];
#pragma unroll
      for (int nt = 0; nt < 3; nt++) {
        acc[mt][nt] = __builtin_amdgcn_mfma_f32_16x16x32_bf16(a0, bf0[nt], acc[mt][nt], 0, 0, 0);
        acc[mt][nt] = __builtin_amdgcn_mfma_f32_16x16x32_bf16(a1, bf1[nt], acc[mt][nt], 0, 0, 0);
      }
    }

    // contract i with ar (lane-consecutive 8B loads), reduce over lane groups
    float pv[3];
#pragma unroll
    for (int nt = 0; nt < 3; nt++) {
      float p = 0.f;
#pragma unroll
      for (int mt = 0; mt < 3; mt++) {
        short4 s = *(const short4*)&arg[(nt * 3 + mt) * 256 + lane * 4];
        p += bf2f((u16)s.x) * acc[mt][nt][0] + bf2f((u16)s.y) * acc[mt][nt][1]
           + bf2f((u16)s.z) * acc[mt][nt][2] + bf2f((u16)s.w) * acc[mt][nt][3];
      }
      p += __shfl_xor(p, 16);
      p += __shfl_xor(p, 32);
      pv[nt] = p;             // all lanes: value for w = nt*16 + lr
    }

    // lanes 0..47 write w=lane: PE depthwise 3x3 from resident v + store
    if (lane < 48) {
      float a = (lane < 16) ? pv[0] : (lane < 32 ? pv[1] : pv[2]);
      a += pb;
      int ww = lane;
#pragma unroll
      for (int kh = -1; kh <= 1; kh++) {
        int ih = h + kh;
        if (ih < 0 || ih > 47) continue;
#pragma unroll
        for (int kw = -1; kw <= 1; kw++) {
          int jw = ww + kw;
          if (jw < 0 || jw > 47) continue;
          a += pw[(kh + 1) * 3 + (kw + 1)] * bf2f(vA[(vrow0 + ih) * 72 + jw]);
        }
      }
      yg[h * 48 + ww] = a;
    }
  }
}

// ---------------------------------------------------------------------------
extern "C" void kernel_launch(void* const* d_in, const int* in_sizes, int n_in,
                              void* d_out, int out_size, void* d_ws, size_t ws_size,
                              hipStream_t stream) {
  const float* x      = (const float*)d_in[0];
  const float* rcv_w  = (const float*)d_in[1];
  const float* rcv_b  = (const float*)d_in[2];
  const float* pe_w   = (const float*)d_in[3];
  const float* pe_b   = (const float*)d_in[4];
  const float* proj_w = (const float*)d_in[5];
  const float* proj_b = (const float*)d_in[6];
  float* out = (float*)d_out;

  char* ws = (char*)d_ws;
  float* rcv = (float*)ws;                         // 28,311,552 B
  u16*   arF = (u16*)(ws + 28311552);              //  7,077,888 B
  u16*   awF = (u16*)(ws + 35389440);              //  9,437,184 B
  float* y   = (float*)(ws + 44826624);            //  9,437,184 B
  u16*   Whr = (u16*)(ws + 54263808);              //    393,216 B
  u16*   Wlr = (u16*)(ws + 54657024);              //    393,216 B
  u16*   Whp = (u16*)(ws + 55050240);              //    131,072 B
  u16*   Wlp = (u16*)(ws + 55181312);              //    131,072 B

  splitw_kernel<<<dim3(256), 256, 0, stream>>>(rcv_w, Whr, Wlr, proj_w, Whp, Wlp);
  gemm_mfma_kernel<false><<<dim3(72 * 12), 256, 0, stream>>>(Whr, Wlr, rcv_b, x, rcv, 768);
  row_attn_kernel<<<dim3(8, 8, 4), 256, 0, stream>>>(rcv, arF);
  col_attn_kernel<<<dim3(8, 8, 4), 256, 0, stream>>>(rcv, awF);
  attn_main_kernel<<<dim3(1024), 256, 0, stream>>>(rcv, arF, awF, pe_w, pe_b, y);
  gemm_mfma_kernel<true><<<dim3(72 * 4), 256, 0, stream>>>(Whp, Wlp, proj_b, y, out, 256);
}

// Round 12
// 158.091 us; speedup vs baseline: 1.3214x; 1.3214x over previous
//
#include <hip/hip_runtime.h>

#define S_ 2304   // 48*48

typedef unsigned short u16;
typedef __attribute__((ext_vector_type(8))) short bf16x8;
typedef __attribute__((ext_vector_type(4))) float f32x4;

static __device__ __forceinline__ u16 f2bf(float x) {
  union { float f; unsigned u; } v; v.f = x;
  unsigned r = v.u + 0x7FFFu + ((v.u >> 16) & 1u);
  return (u16)(r >> 16);
}
static __device__ __forceinline__ float bf2f(u16 h) {
  union { unsigned u; float f; } v; v.u = ((unsigned)h) << 16; return v.f;
}

// ---------------------------------------------------------------------------
// Weight split (both weight tensors in one dispatch).
// ---------------------------------------------------------------------------
__global__ __launch_bounds__(256) void splitw_kernel(
    const float* __restrict__ w0, u16* __restrict__ wh0, u16* __restrict__ wl0,
    const float* __restrict__ w1, u16* __restrict__ wh1, u16* __restrict__ wl1)
{
  const float* w; u16 *wh, *wl; int id;
  if (blockIdx.x < 192) { w = w0; wh = wh0; wl = wl0; id = blockIdx.x * 256 + threadIdx.x; }
  else { w = w1; wh = wh1; wl = wl1; id = (blockIdx.x - 192) * 256 + threadIdx.x; }
  float4 v = ((const float4*)w)[id];
  short4 h, l;
  float f[4] = {v.x, v.y, v.z, v.w};
  u16 hh[4], ll[4];
#pragma unroll
  for (int q = 0; q < 4; q++) {
    hh[q] = f2bf(f[q]);
    ll[q] = f2bf(f[q] - bf2f(hh[q]));
  }
  h.x = hh[0]; h.y = hh[1]; h.z = hh[2]; h.w = hh[3];
  l.x = ll[0]; l.y = ll[1]; l.z = ll[2]; l.w = ll[3];
  ((short4*)wh)[id] = h;
  ((short4*)wl)[id] = l;
}

// ---------------------------------------------------------------------------
// Split-transpose: in[b][256][2304] fp32 -> outh (+outl if WRITEL)
// [b][2304][256] bf16. 64x64 tiles via LDS. Grid (36,4,4b).
// ---------------------------------------------------------------------------
template <bool WRITEL>
__global__ __launch_bounds__(256) void split_transpose_kernel(
    const float* __restrict__ in, u16* __restrict__ outh, u16* __restrict__ outl)
{
  __shared__ unsigned tile[64][65];
  const int s0 = blockIdx.x * 64, c0 = blockIdx.y * 64, b = blockIdx.z;
  const float* inb = in + (size_t)b * 256 * S_;
  u16* oh = outh + (size_t)b * S_ * 256;
  u16* ol = outl + (size_t)b * S_ * 256;
  const int tid = threadIdx.x;
#pragma unroll
  for (int it = 0; it < 4; it++) {
    int id = tid + it * 256;
    int c = id >> 4, s4 = (id & 15) * 4;
    float4 v = *(const float4*)&inb[(size_t)(c0 + c) * S_ + s0 + s4];
    float f[4] = {v.x, v.y, v.z, v.w};
#pragma unroll
    for (int q = 0; q < 4; q++) {
      u16 h = f2bf(f[q]);
      u16 l = f2bf(f[q] - bf2f(h));
      tile[s4 + q][c] = (unsigned)h | ((unsigned)l << 16);
    }
  }
  __syncthreads();
#pragma unroll
  for (int it = 0; it < 4; it++) {
    int id = tid + it * 256;
    int s = id >> 4, c4 = (id & 15) * 4;
    short4 h, l;
    unsigned p0 = tile[s][c4 + 0], p1 = tile[s][c4 + 1];
    unsigned p2 = tile[s][c4 + 2], p3 = tile[s][c4 + 3];
    h.x = (short)(p0 & 0xffff); h.y = (short)(p1 & 0xffff);
    h.z = (short)(p2 & 0xffff); h.w = (short)(p3 & 0xffff);
    *(short4*)&oh[(size_t)(s0 + s) * 256 + c0 + c4] = h;
    if (WRITEL) {
      l.x = (short)(p0 >> 16); l.y = (short)(p1 >> 16);
      l.z = (short)(p2 >> 16); l.w = (short)(p3 >> 16);
      *(short4*)&ol[(size_t)(s0 + s) * 256 + c0 + c4] = l;
    }
  }
}

// ---------------------------------------------------------------------------
// MFMA split-bf16 GEMM (r10 form): B direct from XT global with reg prefetch.
// XLO=false: Out = (Wh+Wl)*Xh. BM=64, BN=128, 864 blocks for M=768.
// ---------------------------------------------------------------------------
template <bool XLO>
__global__ __launch_bounds__(256) void gemm_mfma_kernel(
    const u16* __restrict__ Wh, const u16* __restrict__ Wl,
    const float* __restrict__ bias,
    const u16* __restrict__ XTh, const u16* __restrict__ XTl,
    float* __restrict__ Out, int M)
{
  __shared__ u16 wAh[2][64 * 40];
  __shared__ u16 wAl[2][64 * 40];
  const int MB = M >> 6;
  const int xcd = blockIdx.x & 7;
  const int idx = blockIdx.x >> 3;
  const int g = xcd * 9 + idx / MB;
  const int mb = idx % MB;
  const int nb = g % 18, b = g / 18;
  const int m0 = mb * 64, n0 = nb * 128;
  const int tid = threadIdx.x;
  const int wv = tid >> 6, lane = tid & 63;
  const int lr = lane & 15, lg = lane >> 4;
  const bf16x8 zv = {0, 0, 0, 0, 0, 0, 0, 0};

  const u16* xbh = XTh + ((size_t)b * S_ + n0 + wv * 32) * 256;
  const u16* xbl = XTl + ((size_t)b * S_ + n0 + wv * 32) * 256;

  f32x4 acc[4][2];
#pragma unroll
  for (int mt = 0; mt < 4; mt++)
#pragma unroll
    for (int nt = 0; nt < 2; nt++) acc[mt][nt] = (f32x4){0.f, 0.f, 0.f, 0.f};

#define STAGE_W(t, buf)                                                      \
  {                                                                          \
    _Pragma("unroll")                                                        \
    for (int r = 0; r < 2; r++) {                                            \
      int id = tid + r * 256;                                                \
      int m = id >> 3, k4 = (id & 7) * 4;                                    \
      *(short4*)&wAh[buf][m * 40 + k4] =                                     \
          *(const short4*)&Wh[(size_t)(m0 + m) * 256 + (t) * 32 + k4];       \
      *(short4*)&wAl[buf][m * 40 + k4] =                                     \
          *(const short4*)&Wl[(size_t)(m0 + m) * 256 + (t) * 32 + k4];       \
    }                                                                        \
  }

  STAGE_W(0, 0);
  bf16x8 cbh[2], cbl[2];
#pragma unroll
  for (int nt = 0; nt < 2; nt++) {
    size_t off = (size_t)(nt * 16 + lr) * 256 + lg * 8;
    cbh[nt] = *(const bf16x8*)&xbh[off];
    if (XLO) cbl[nt] = *(const bf16x8*)&xbl[off];
  }
  __syncthreads();

  for (int t = 0; t < 8; t++) {
    int buf = t & 1;
    if (t < 7) STAGE_W(t + 1, buf ^ 1);

    bf16x8 nbh[2], nbl[2];
    if (t < 7) {
#pragma unroll
      for (int nt = 0; nt < 2; nt++) {
        size_t off = (size_t)(nt * 16 + lr) * 256 + (t + 1) * 32 + lg * 8;
        nbh[nt] = *(const bf16x8*)&xbh[off];
        if (XLO) nbl[nt] = *(const bf16x8*)&xbl[off];
      }
    } else {
#pragma unroll
      for (int nt = 0; nt < 2; nt++) { nbh[nt] = zv; if (XLO) nbl[nt] = zv; }
    }

    bf16x8 ah[4], al[4];
#pragma unroll
    for (int mt = 0; mt < 4; mt++) {
      ah[mt] = *(const bf16x8*)&wAh[buf][(mt * 16 + lr) * 40 + lg * 8];
      al[mt] = *(const bf16x8*)&wAl[buf][(mt * 16 + lr) * 40 + lg * 8];
    }
#pragma unroll
    for (int mt = 0; mt < 4; mt++)
#pragma unroll
      for (int nt = 0; nt < 2; nt++) {
        acc[mt][nt] = __builtin_amdgcn_mfma_f32_16x16x32_bf16(ah[mt], cbh[nt], acc[mt][nt], 0, 0, 0);
        if (XLO)
          acc[mt][nt] = __builtin_amdgcn_mfma_f32_16x16x32_bf16(ah[mt], cbl[nt], acc[mt][nt], 0, 0, 0);
        acc[mt][nt] = __builtin_amdgcn_mfma_f32_16x16x32_bf16(al[mt], cbh[nt], acc[mt][nt], 0, 0, 0);
      }
    __syncthreads();
#pragma unroll
    for (int nt = 0; nt < 2; nt++) { cbh[nt] = nbh[nt]; if (XLO) cbl[nt] = nbl[nt]; }
  }

  float* ob = Out + (size_t)b * M * S_;
#pragma unroll
  for (int mt = 0; mt < 4; mt++) {
    float4 b4 = *(const float4*)&bias[m0 + mt * 16 + lg * 4];
    float bv[4] = {b4.x, b4.y, b4.z, b4.w};
#pragma unroll
    for (int nt = 0; nt < 2; nt++) {
      int s = n0 + wv * 32 + nt * 16 + lr;
#pragma unroll
      for (int r = 0; r < 4; r++) {
        int m = m0 + mt * 16 + lg * 4 + r;
        ob[(size_t)m * S_ + s] = acc[mt][nt][r] + bv[r];
      }
    }
  }
#undef STAGE_W
}

// ---------------------------------------------------------------------------
// Proj GEMM, BN=64 for occupancy: M=256 -> 576 blocks (vs 288 at BN=128).
// 4 waves, each 32m x 32s. Always 3-term. BM=64, K=256.
// ---------------------------------------------------------------------------
__global__ __launch_bounds__(256) void gemm_n64_kernel(
    const u16* __restrict__ Wh, const u16* __restrict__ Wl,
    const float* __restrict__ bias,
    const u16* __restrict__ XTh, const u16* __restrict__ XTl,
    float* __restrict__ Out)
{
  __shared__ u16 wAh[2][64 * 40];
  __shared__ u16 wAl[2][64 * 40];
  const int M = 256, MB = 4;
  const int xcd = blockIdx.x & 7;
  const int idx = blockIdx.x >> 3;          // 0..71
  const int g = xcd * 18 + idx / MB;        // 0..143 = (nb, b)
  const int mb = idx % MB;
  const int nb = g % 36, b = g / 36;
  const int m0 = mb * 64, n0 = nb * 64;
  const int tid = threadIdx.x;
  const int wv = tid >> 6, lane = tid & 63;
  const int wm = wv >> 1, wsd = wv & 1;
  const int lr = lane & 15, lg = lane >> 4;
  const bf16x8 zv = {0, 0, 0, 0, 0, 0, 0, 0};

  const u16* xbh = XTh + ((size_t)b * S_ + n0 + wsd * 32) * 256;
  const u16* xbl = XTl + ((size_t)b * S_ + n0 + wsd * 32) * 256;

  f32x4 acc[2][2];
#pragma unroll
  for (int mt = 0; mt < 2; mt++)
#pragma unroll
    for (int nt = 0; nt < 2; nt++) acc[mt][nt] = (f32x4){0.f, 0.f, 0.f, 0.f};

#define STAGE_W(t, buf)                                                      \
  {                                                                          \
    _Pragma("unroll")                                                        \
    for (int r = 0; r < 2; r++) {                                            \
      int id = tid + r * 256;                                                \
      int m = id >> 3, k4 = (id & 7) * 4;                                    \
      *(short4*)&wAh[buf][m * 40 + k4] =                                     \
          *(const short4*)&Wh[(size_t)(m0 + m) * 256 + (t) * 32 + k4];       \
      *(short4*)&wAl[buf][m * 40 + k4] =                                     \
          *(const short4*)&Wl[(size_t)(m0 + m) * 256 + (t) * 32 + k4];       \
    }                                                                        \
  }

  STAGE_W(0, 0);
  bf16x8 cbh[2], cbl[2];
#pragma unroll
  for (int nt = 0; nt < 2; nt++) {
    size_t off = (size_t)(nt * 16 + lr) * 256 + lg * 8;
    cbh[nt] = *(const bf16x8*)&xbh[off];
    cbl[nt] = *(const bf16x8*)&xbl[off];
  }
  __syncthreads();

  for (int t = 0; t < 8; t++) {
    int buf = t & 1;
    if (t < 7) STAGE_W(t + 1, buf ^ 1);

    bf16x8 nbh[2], nbl[2];
    if (t < 7) {
#pragma unroll
      for (int nt = 0; nt < 2; nt++) {
        size_t off = (size_t)(nt * 16 + lr) * 256 + (t + 1) * 32 + lg * 8;
        nbh[nt] = *(const bf16x8*)&xbh[off];
        nbl[nt] = *(const bf16x8*)&xbl[off];
      }
    } else {
#pragma unroll
      for (int nt = 0; nt < 2; nt++) { nbh[nt] = zv; nbl[nt] = zv; }
    }

    bf16x8 ah[2], al[2];
#pragma unroll
    for (int mt = 0; mt < 2; mt++) {
      ah[mt] = *(const bf16x8*)&wAh[buf][(wm * 32 + mt * 16 + lr) * 40 + lg * 8];
      al[mt] = *(const bf16x8*)&wAl[buf][(wm * 32 + mt * 16 + lr) * 40 + lg * 8];
    }
#pragma unroll
    for (int mt = 0; mt < 2; mt++)
#pragma unroll
      for (int nt = 0; nt < 2; nt++) {
        acc[mt][nt] = __builtin_amdgcn_mfma_f32_16x16x32_bf16(ah[mt], cbh[nt], acc[mt][nt], 0, 0, 0);
        acc[mt][nt] = __builtin_amdgcn_mfma_f32_16x16x32_bf16(ah[mt], cbl[nt], acc[mt][nt], 0, 0, 0);
        acc[mt][nt] = __builtin_amdgcn_mfma_f32_16x16x32_bf16(al[mt], cbh[nt], acc[mt][nt], 0, 0, 0);
      }
    __syncthreads();
#pragma unroll
    for (int nt = 0; nt < 2; nt++) { cbh[nt] = nbh[nt]; cbl[nt] = nbl[nt]; }
  }

  float* ob = Out + (size_t)b * M * S_;
#pragma unroll
  for (int mt = 0; mt < 2; mt++) {
    float4 b4 = *(const float4*)&bias[m0 + wm * 32 + mt * 16 + lg * 4];
    float bv[4] = {b4.x, b4.y, b4.z, b4.w};
#pragma unroll
    for (int nt = 0; nt < 2; nt++) {
      int s = n0 + wsd * 32 + nt * 16 + lr;
#pragma unroll
      for (int r = 0; r < 4; r++) {
        int m = m0 + wm * 32 + mt * 16 + lg * 4 + r;
        ob[(size_t)m * S_ + s] = acc[mt][nt][r] + bv[r];
      }
    }
  }
#undef STAGE_W
}

// ---------------------------------------------------------------------------
// Row attention -> arF fragment-major, now FP32 (no unpack in attn_main).
// ---------------------------------------------------------------------------
__global__ __launch_bounds__(256) void row_attn_kernel(
    const float* __restrict__ rcv, float* __restrict__ arF)
{
  __shared__ u16  rq[16 * 2304];
  __shared__ float rk[16 * 48];
  __shared__ float Sm[48 * 49];
  __shared__ float cmax[48], crs[48];
  const int hg = blockIdx.x, n = blockIdx.y, b = blockIdx.z;
  const float* base = rcv + ((size_t)b * 768 + n * 96) * S_;
  const int tid = threadIdx.x;

  for (int id = tid; id < 9216; id += 256) {
    float4 v = *(const float4*)&base[id * 4];
    short4 s;
    s.x = (short)f2bf(v.x); s.y = (short)f2bf(v.y);
    s.z = (short)f2bf(v.z); s.w = (short)f2bf(v.w);
    *(short4*)&rq[id * 4] = s;
  }

  for (int hh = 0; hh < 6; hh++) {
    int h = hg * 6 + hh;
    for (int id = tid; id < 768; id += 256) {
      int d = id / 48, w = id % 48;
      rk[id] = base[(size_t)(16 + d) * S_ + h * 48 + w];
    }
    __syncthreads();
    for (int id = tid; id < 2304; id += 256) {
      int i = id / 48, w = id % 48;
      float s = 0.f;
#pragma unroll
      for (int d = 0; d < 16; d++)
        s += bf2f(rq[d * 2304 + i * 48 + w]) * rk[d * 48 + w];
      Sm[i * 49 + w] = s * 0.25f;
    }
    __syncthreads();
    if (tid < 192) {
      int w = tid >> 2, e = tid & 3;
      float m = -1e30f;
      for (int i = e; i < 48; i += 4) m = fmaxf(m, Sm[i * 49 + w]);
      m = fmaxf(m, __shfl_xor(m, 1));
      m = fmaxf(m, __shfl_xor(m, 2));
      float s = 0.f;
      for (int i = e; i < 48; i += 4) s += __expf(Sm[i * 49 + w] - m);
      s += __shfl_xor(s, 1);
      s += __shfl_xor(s, 2);
      cmax[w] = m; crs[w] = 1.0f / s;
    }
    __syncthreads();
    float* dst = arF + ((size_t)(b * 8 + n) * 48 + h) * 2304;
    for (int id = tid; id < 576; id += 256) {
      int nt = id / 192, rem = id % 192, mt = rem / 64, l = rem % 64;
      int w = nt * 16 + (l & 15);
      int i0 = mt * 16 + ((l >> 4) << 2);
      float4 o;
      o.x = __expf(Sm[(i0 + 0) * 49 + w] - cmax[w]) * crs[w];
      o.y = __expf(Sm[(i0 + 1) * 49 + w] - cmax[w]) * crs[w];
      o.z = __expf(Sm[(i0 + 2) * 49 + w] - cmax[w]) * crs[w];
      o.w = __expf(Sm[(i0 + 3) * 49 + w] - cmax[w]) * crs[w];
      *(float4*)&dst[id * 4] = o;   // coalesced
    }
    __syncthreads();
  }
}

// ---------------------------------------------------------------------------
// Col attention -> awF fragment-major bf16 (MFMA B-operand), wave-par softmax.
// ---------------------------------------------------------------------------
__global__ __launch_bounds__(256) void col_attn_kernel(
    const float* __restrict__ rcv, u16* __restrict__ awF)
{
  __shared__ float cq[16 * 48], ck[16 * 48];
  __shared__ float Tm[48 * 49];
  __shared__ float rmax[48], rrs[48];
  const int hg = blockIdx.x, n = blockIdx.y, b = blockIdx.z;
  const float* base = rcv + ((size_t)b * 768 + n * 96 + 32) * S_;
  const int tid = threadIdx.x;

  for (int hh = 0; hh < 6; hh++) {
    int h = hg * 6 + hh;
    for (int id = tid; id < 768; id += 256) {
      int d = id / 48, j = id % 48;
      cq[id] = base[(size_t)d * S_ + h * 48 + j];
      ck[id] = base[(size_t)(16 + d) * S_ + h * 48 + j];
    }
    __syncthreads();
    for (int id = tid; id < 2304; id += 256) {
      int w = id / 48, j = id % 48;
      float t = 0.f;
#pragma unroll
      for (int d = 0; d < 16; d++)
        t += ck[d * 48 + w] * cq[d * 48 + j];
      Tm[w * 49 + j] = t * 0.25f;
    }
    __syncthreads();
    if (tid < 192) {
      int w = tid >> 2, e = tid & 3;
      float m = -1e30f;
      for (int j = e; j < 48; j += 4) m = fmaxf(m, Tm[w * 49 + j]);
      m = fmaxf(m, __shfl_xor(m, 1));
      m = fmaxf(m, __shfl_xor(m, 2));
      float s = 0.f;
      for (int j = e; j < 48; j += 4) s += __expf(Tm[w * 49 + j] - m);
      s += __shfl_xor(s, 1);
      s += __shfl_xor(s, 2);
      rmax[w] = m; rrs[w] = 1.0f / s;
    }
    __syncthreads();
    u16* dst = awF + ((size_t)(b * 8 + n) * 48 + h) * 3072;
    for (int id = tid; id < 384; id += 256) {
      int nt = id / 128, rem = id % 128, ks = rem / 64, l = rem % 64;
      int w = nt * 16 + (l & 15);
      int j0 = ks * 32 + ((l >> 4) << 3);
      u16 t8[8];
#pragma unroll
      for (int e = 0; e < 8; e++) {
        int j = j0 + e;
        t8[e] = (j < 48) ? f2bf(__expf(Tm[w * 49 + j] - rmax[w]) * rrs[w]) : (u16)0;
      }
      short4 o0, o1;
      o0.x = (short)t8[0]; o0.y = (short)t8[1]; o0.z = (short)t8[2]; o0.w = (short)t8[3];
      o1.x = (short)t8[4]; o1.y = (short)t8[5]; o1.z = (short)t8[6]; o1.w = (short)t8[7];
      *(short4*)&dst[id * 8]     = o0;
      *(short4*)&dst[id * 8 + 4] = o1;
    }
    __syncthreads();
  }
}

// ---------------------------------------------------------------------------
// Main contraction + PE conv (r10 geometry: 2048 blocks, 2 v-planes,
// 4 waves = 2 planes x 2 h-halves, fragment-major coalesced loads;
// ar now fp32 -> no unpack in the dot).
// ---------------------------------------------------------------------------
__global__ __launch_bounds__(256) void attn_main_kernel(
    const float* __restrict__ rcv, const float* __restrict__ arF,
    const u16* __restrict__ awF, const float* __restrict__ pe_w,
    const float* __restrict__ pe_b, float* __restrict__ y)
{
  __shared__ u16 vA[96 * 72];         // 13824 B
  const int id0 = blockIdx.x;
  const int n = id0 & 7;              // XCD swizzle
  const int rest = id0 >> 3;          // 0..255
  const int b = rest >> 6;
  const int inner = rest & 63;
  const int dchunk = inner >> 2;      // 0..15 (2 planes each)
  const int hc = inner & 3;
  const int tid = threadIdx.x;
  const int wave = tid >> 6, lane = tid & 63;
  const int dl = wave >> 1, half = wave & 1;
  const int h0 = hc * 12 + half * 6;
  const int lr = lane & 15, lg = lane >> 4;

  for (int id = tid; id < 96 * 24; id += 256) {
    int row = id / 24, col = 48 + id % 24;
    vA[row * 72 + col] = 0;
  }
  const float* vbase = rcv + ((size_t)b * 768 + n * 96 + 64 + dchunk * 2) * S_;
  for (int id = tid; id < 1152; id += 256) {
    int dl2 = id / 576, rem = id % 576;
    int i = rem / 12, j4 = (rem % 12) * 4;
    float4 v = *(const float4*)&vbase[(size_t)dl2 * S_ + i * 48 + j4];
    short4 s;
    s.x = (short)f2bf(v.x); s.y = (short)f2bf(v.y);
    s.z = (short)f2bf(v.z); s.w = (short)f2bf(v.w);
    *(short4*)&vA[(dl2 * 48 + i) * 72 + j4] = s;
  }
  __syncthreads();   // the only barrier

  const size_t bn48 = (size_t)(b * 8 + n) * 48;
  const int c = n * 32 + dchunk * 2 + dl;
  float pw[9];
#pragma unroll
  for (int t = 0; t < 9; t++) pw[t] = pe_w[c * 9 + t];
  const float pb = pe_b[c];
  float* yg = y + ((size_t)b * 256 + c) * S_;
  const int vrow0 = dl * 48;

  for (int hh = 0; hh < 6; hh++) {
    int h = h0 + hh;
    const u16*   awg = awF + (bn48 + h) * 3072;
    const float* arg = arF + (bn48 + h) * 2304;

    bf16x8 bf0[3], bf1[3];
#pragma unroll
    for (int nt = 0; nt < 3; nt++) {
      bf0[nt] = *(const bf16x8*)&awg[nt * 1024 + lane * 8];
      bf1[nt] = *(const bf16x8*)&awg[nt * 1024 + 512 + lane * 8];
    }

    f32x4 acc[3][3];
#pragma unroll
    for (int mt = 0; mt < 3; mt++)
#pragma unroll
      for (int nt = 0; nt < 3; nt++) acc[mt][nt] = (f32x4){0.f, 0.f, 0.f, 0.f};

#pragma unroll
    for (int mt = 0; mt < 3; mt++) {
      bf16x8 a0 = *(const bf16x8*)&vA[(vrow0 + mt * 16 + lr) * 72 + lg * 8];
      bf16x8 a1 = *(const bf16x8*)&vA[(vrow0 + mt * 16 + lr) * 72 + 32 + lg * 8];
#pragma unroll
      for (int nt = 0; nt < 3; nt++) {
        acc[mt][nt] = __builtin_amdgcn_mfma_f32_16x16x32_bf16(a0, bf0[nt], acc[mt][nt], 0, 0, 0);
        acc[mt][nt] = __builtin_amdgcn_mfma_f32_16x16x32_bf16(a1, bf1[nt], acc[mt][nt], 0, 0, 0);
      }
    }

    float pv[3];
#pragma unroll
    for (int nt = 0; nt < 3; nt++) {
      float p = 0.f;
#pragma unroll
      for (int mt = 0; mt < 3; mt++) {
        float4 s = *(const float4*)&arg[(nt * 3 + mt) * 256 + lane * 4];
        p += s.x * acc[mt][nt][0] + s.y * acc[mt][nt][1]
           + s.z * acc[mt][nt][2] + s.w * acc[mt][nt][3];
      }
      p += __shfl_xor(p, 16);
      p += __shfl_xor(p, 32);
      pv[nt] = p;
    }

    if (lane < 48) {
      float a = (lane < 16) ? pv[0] : (lane < 32 ? pv[1] : pv[2]);
      a += pb;
      int ww = lane;
#pragma unroll
      for (int kh = -1; kh <= 1; kh++) {
        int ih = h + kh;
        if (ih < 0 || ih > 47) continue;
#pragma unroll
        for (int kw = -1; kw <= 1; kw++) {
          int jw = ww + kw;
          if (jw < 0 || jw > 47) continue;
          a += pw[(kh + 1) * 3 + (kw + 1)] * bf2f(vA[(vrow0 + ih) * 72 + jw]);
        }
      }
      yg[h * 48 + ww] = a;
    }
  }
}

// ---------------------------------------------------------------------------
extern "C" void kernel_launch(void* const* d_in, const int* in_sizes, int n_in,
                              void* d_out, int out_size, void* d_ws, size_t ws_size,
                              hipStream_t stream) {
  const float* x      = (const float*)d_in[0];
  const float* rcv_w  = (const float*)d_in[1];
  const float* rcv_b  = (const float*)d_in[2];
  const float* pe_w   = (const float*)d_in[3];
  const float* pe_b   = (const float*)d_in[4];
  const float* proj_w = (const float*)d_in[5];
  const float* proj_b = (const float*)d_in[6];
  float* out = (float*)d_out;

  char* ws = (char*)d_ws;
  float* rcv = (float*)ws;                         // 0          28,311,552 B
  // region A: xTh (4.7 MB, dead after gemm#1) then arF fp32 (14.2 MB) aliases it
  u16*   xTh = (u16*)(ws + 28311552);              // 4,718,592 B
  float* arF = (float*)(ws + 28311552);            // 14,155,776 B (after xTh dead)
  // region B: awF (9.4 MB, dead after attn_main) -> yTh/yTl alias it
  u16*   awF = (u16*)(ws + 42467328);              // 9,437,184 B
  u16*   yTh = (u16*)(ws + 42467328);              // 4,718,592 B
  u16*   yTl = (u16*)(ws + 47185920);              // 4,718,592 B
  float* y   = (float*)(ws + 51904512);            // 9,437,184 B
  u16*   Whr = (u16*)(ws + 61341696);              //   393,216 B
  u16*   Wlr = (u16*)(ws + 61734912);              //   393,216 B
  u16*   Whp = (u16*)(ws + 62128128);              //   131,072 B
  u16*   Wlp = (u16*)(ws + 62259200);              //   131,072 B  (end ~62.4 MB)

  splitw_kernel<<<dim3(256), 256, 0, stream>>>(rcv_w, Whr, Wlr, proj_w, Whp, Wlp);
  split_transpose_kernel<false><<<dim3(36, 4, 4), 256, 0, stream>>>(x, xTh, xTh);
  gemm_mfma_kernel<false><<<dim3(72 * 12), 256, 0, stream>>>(Whr, Wlr, rcv_b, xTh, xTh, rcv, 768);
  row_attn_kernel<<<dim3(8, 8, 4), 256, 0, stream>>>(rcv, arF);
  col_attn_kernel<<<dim3(8, 8, 4), 256, 0, stream>>>(rcv, awF);
  attn_main_kernel<<<dim3(2048), 256, 0, stream>>>(rcv, arF, awF, pe_w, pe_b, y);
  split_transpose_kernel<true><<<dim3(36, 4, 4), 256, 0, stream>>>(y, yTh, yTl);
  gemm_n64_kernel<<<dim3(576), 256, 0, stream>>>(Whp, Wlp, proj_b, yTh, yTl, out);
}

// Round 13
// 121.538 us; speedup vs baseline: 1.7189x; 1.3008x over previous
//
#include <hip/hip_runtime.h>

#define S_ 2304   // 48*48

typedef unsigned short u16;
typedef __attribute__((ext_vector_type(8))) short bf16x8;
typedef __attribute__((ext_vector_type(4))) float f32x4;

static __device__ __forceinline__ u16 f2bf(float x) {
  union { float f; unsigned u; } v; v.f = x;
  unsigned r = v.u + 0x7FFFu + ((v.u >> 16) & 1u);
  return (u16)(r >> 16);
}
static __device__ __forceinline__ float bf2f(u16 h) {
  union { unsigned u; float f; } v; v.u = ((unsigned)h) << 16; return v.f;
}
static __device__ __forceinline__ float bflo(unsigned p) {   // low bf16 of packed pair
  union { unsigned u; float f; } v; v.u = p << 16; return v.f;
}
static __device__ __forceinline__ float bfhi(unsigned p) {   // high bf16 of packed pair
  union { unsigned u; float f; } v; v.u = p & 0xFFFF0000u; return v.f;
}

// ---------------------------------------------------------------------------
// Prep: weight split (blocks 0..255) + x split-transpose h-only (256..831).
// ---------------------------------------------------------------------------
__global__ __launch_bounds__(256) void prep_kernel(
    const float* __restrict__ w0, u16* __restrict__ wh0, u16* __restrict__ wl0,
    const float* __restrict__ w1, u16* __restrict__ wh1, u16* __restrict__ wl1,
    const float* __restrict__ x, u16* __restrict__ xTh)
{
  __shared__ u16 tile[64][65];
  const int bid = blockIdx.x;
  const int tid = threadIdx.x;
  if (bid < 256) {
    const float* w; u16 *wh, *wl; int id;
    if (bid < 192) { w = w0; wh = wh0; wl = wl0; id = bid * 256 + tid; }
    else { w = w1; wh = wh1; wl = wl1; id = (bid - 192) * 256 + tid; }
    float4 v = ((const float4*)w)[id];
    short4 h, l;
    float f[4] = {v.x, v.y, v.z, v.w};
    u16 hh[4], ll[4];
#pragma unroll
    for (int q = 0; q < 4; q++) {
      hh[q] = f2bf(f[q]);
      ll[q] = f2bf(f[q] - bf2f(hh[q]));
    }
    h.x = hh[0]; h.y = hh[1]; h.z = hh[2]; h.w = hh[3];
    l.x = ll[0]; l.y = ll[1]; l.z = ll[2]; l.w = ll[3];
    ((short4*)wh)[id] = h;
    ((short4*)wl)[id] = l;
    return;
  }
  // transpose part: bid2 0..575 -> (s0 36, c0 4, b 4)
  const int bid2 = bid - 256;
  const int s0 = (bid2 % 36) * 64, c0 = ((bid2 / 36) % 4) * 64, b = bid2 / 144;
  const float* inb = x + (size_t)b * 256 * S_;
  u16* oh = xTh + (size_t)b * S_ * 256;
#pragma unroll
  for (int it = 0; it < 4; it++) {
    int id = tid + it * 256;
    int c = id >> 4, s4 = (id & 15) * 4;
    float4 v = *(const float4*)&inb[(size_t)(c0 + c) * S_ + s0 + s4];
    tile[s4 + 0][c] = f2bf(v.x);
    tile[s4 + 1][c] = f2bf(v.y);
    tile[s4 + 2][c] = f2bf(v.z);
    tile[s4 + 3][c] = f2bf(v.w);
  }
  __syncthreads();
#pragma unroll
  for (int it = 0; it < 4; it++) {
    int id = tid + it * 256;
    int s = id >> 4, c4 = (id & 15) * 4;
    short4 h;
    h.x = (short)tile[s][c4 + 0]; h.y = (short)tile[s][c4 + 1];
    h.z = (short)tile[s][c4 + 2]; h.w = (short)tile[s][c4 + 3];
    *(short4*)&oh[(size_t)(s0 + s) * 256 + c0 + c4] = h;
  }
}

// ---------------------------------------------------------------------------
// Split-transpose (h+l) for y before proj. Grid (36,4,4).
// ---------------------------------------------------------------------------
__global__ __launch_bounds__(256) void split_transpose_kernel(
    const float* __restrict__ in, u16* __restrict__ outh, u16* __restrict__ outl)
{
  __shared__ unsigned tile[64][65];
  const int s0 = blockIdx.x * 64, c0 = blockIdx.y * 64, b = blockIdx.z;
  const float* inb = in + (size_t)b * 256 * S_;
  u16* oh = outh + (size_t)b * S_ * 256;
  u16* ol = outl + (size_t)b * S_ * 256;
  const int tid = threadIdx.x;
#pragma unroll
  for (int it = 0; it < 4; it++) {
    int id = tid + it * 256;
    int c = id >> 4, s4 = (id & 15) * 4;
    float4 v = *(const float4*)&inb[(size_t)(c0 + c) * S_ + s0 + s4];
    float f[4] = {v.x, v.y, v.z, v.w};
#pragma unroll
    for (int q = 0; q < 4; q++) {
      u16 h = f2bf(f[q]);
      u16 l = f2bf(f[q] - bf2f(h));
      tile[s4 + q][c] = (unsigned)h | ((unsigned)l << 16);
    }
  }
  __syncthreads();
#pragma unroll
  for (int it = 0; it < 4; it++) {
    int id = tid + it * 256;
    int s = id >> 4, c4 = (id & 15) * 4;
    short4 h, l;
    unsigned p0 = tile[s][c4 + 0], p1 = tile[s][c4 + 1];
    unsigned p2 = tile[s][c4 + 2], p3 = tile[s][c4 + 3];
    h.x = (short)(p0 & 0xffff); h.y = (short)(p1 & 0xffff);
    h.z = (short)(p2 & 0xffff); h.w = (short)(p3 & 0xffff);
    l.x = (short)(p0 >> 16); l.y = (short)(p1 >> 16);
    l.z = (short)(p2 >> 16); l.w = (short)(p3 >> 16);
    *(short4*)&oh[(size_t)(s0 + s) * 256 + c0 + c4] = h;
    *(short4*)&ol[(size_t)(s0 + s) * 256 + c0 + c4] = l;
  }
}

// ---------------------------------------------------------------------------
// MFMA split-bf16 GEMM (r10 form), XLO=false: Out=(Wh+Wl)*Xh. BM=64 BN=128.
// ---------------------------------------------------------------------------
template <bool XLO>
__global__ __launch_bounds__(256) void gemm_mfma_kernel(
    const u16* __restrict__ Wh, const u16* __restrict__ Wl,
    const float* __restrict__ bias,
    const u16* __restrict__ XTh, const u16* __restrict__ XTl,
    float* __restrict__ Out, int M)
{
  __shared__ u16 wAh[2][64 * 40];
  __shared__ u16 wAl[2][64 * 40];
  const int MB = M >> 6;
  const int xcd = blockIdx.x & 7;
  const int idx = blockIdx.x >> 3;
  const int g = xcd * 9 + idx / MB;
  const int mb = idx % MB;
  const int nb = g % 18, b = g / 18;
  const int m0 = mb * 64, n0 = nb * 128;
  const int tid = threadIdx.x;
  const int wv = tid >> 6, lane = tid & 63;
  const int lr = lane & 15, lg = lane >> 4;
  const bf16x8 zv = {0, 0, 0, 0, 0, 0, 0, 0};

  const u16* xbh = XTh + ((size_t)b * S_ + n0 + wv * 32) * 256;
  const u16* xbl = XTl + ((size_t)b * S_ + n0 + wv * 32) * 256;

  f32x4 acc[4][2];
#pragma unroll
  for (int mt = 0; mt < 4; mt++)
#pragma unroll
    for (int nt = 0; nt < 2; nt++) acc[mt][nt] = (f32x4){0.f, 0.f, 0.f, 0.f};

#define STAGE_W(t, buf)                                                      \
  {                                                                          \
    _Pragma("unroll")                                                        \
    for (int r = 0; r < 2; r++) {                                            \
      int id = tid + r * 256;                                                \
      int m = id >> 3, k4 = (id & 7) * 4;                                    \
      *(short4*)&wAh[buf][m * 40 + k4] =                                     \
          *(const short4*)&Wh[(size_t)(m0 + m) * 256 + (t) * 32 + k4];       \
      *(short4*)&wAl[buf][m * 40 + k4] =                                     \
          *(const short4*)&Wl[(size_t)(m0 + m) * 256 + (t) * 32 + k4];       \
    }                                                                        \
  }

  STAGE_W(0, 0);
  bf16x8 cbh[2], cbl[2];
#pragma unroll
  for (int nt = 0; nt < 2; nt++) {
    size_t off = (size_t)(nt * 16 + lr) * 256 + lg * 8;
    cbh[nt] = *(const bf16x8*)&xbh[off];
    if (XLO) cbl[nt] = *(const bf16x8*)&xbl[off];
  }
  __syncthreads();

  for (int t = 0; t < 8; t++) {
    int buf = t & 1;
    if (t < 7) STAGE_W(t + 1, buf ^ 1);

    bf16x8 nbh[2], nbl[2];
    if (t < 7) {
#pragma unroll
      for (int nt = 0; nt < 2; nt++) {
        size_t off = (size_t)(nt * 16 + lr) * 256 + (t + 1) * 32 + lg * 8;
        nbh[nt] = *(const bf16x8*)&xbh[off];
        if (XLO) nbl[nt] = *(const bf16x8*)&xbl[off];
      }
    } else {
#pragma unroll
      for (int nt = 0; nt < 2; nt++) { nbh[nt] = zv; if (XLO) nbl[nt] = zv; }
    }

    bf16x8 ah[4], al[4];
#pragma unroll
    for (int mt = 0; mt < 4; mt++) {
      ah[mt] = *(const bf16x8*)&wAh[buf][(mt * 16 + lr) * 40 + lg * 8];
      al[mt] = *(const bf16x8*)&wAl[buf][(mt * 16 + lr) * 40 + lg * 8];
    }
#pragma unroll
    for (int mt = 0; mt < 4; mt++)
#pragma unroll
      for (int nt = 0; nt < 2; nt++) {
        acc[mt][nt] = __builtin_amdgcn_mfma_f32_16x16x32_bf16(ah[mt], cbh[nt], acc[mt][nt], 0, 0, 0);
        if (XLO)
          acc[mt][nt] = __builtin_amdgcn_mfma_f32_16x16x32_bf16(ah[mt], cbl[nt], acc[mt][nt], 0, 0, 0);
        acc[mt][nt] = __builtin_amdgcn_mfma_f32_16x16x32_bf16(al[mt], cbh[nt], acc[mt][nt], 0, 0, 0);
      }
    __syncthreads();
#pragma unroll
    for (int nt = 0; nt < 2; nt++) { cbh[nt] = nbh[nt]; if (XLO) cbl[nt] = nbl[nt]; }
  }

  float* ob = Out + (size_t)b * M * S_;
#pragma unroll
  for (int mt = 0; mt < 4; mt++) {
    float4 b4 = *(const float4*)&bias[m0 + mt * 16 + lg * 4];
    float bv[4] = {b4.x, b4.y, b4.z, b4.w};
#pragma unroll
    for (int nt = 0; nt < 2; nt++) {
      int s = n0 + wv * 32 + nt * 16 + lr;
#pragma unroll
      for (int r = 0; r < 4; r++) {
        int m = m0 + mt * 16 + lg * 4 + r;
        ob[(size_t)m * S_ + s] = acc[mt][nt][r] + bv[r];
      }
    }
  }
#undef STAGE_W
}

// ---------------------------------------------------------------------------
// Proj GEMM, BN=64 (576 blocks for occupancy). 3-term. (r12-proven)
// ---------------------------------------------------------------------------
__global__ __launch_bounds__(256) void gemm_n64_kernel(
    const u16* __restrict__ Wh, const u16* __restrict__ Wl,
    const float* __restrict__ bias,
    const u16* __restrict__ XTh, const u16* __restrict__ XTl,
    float* __restrict__ Out)
{
  __shared__ u16 wAh[2][64 * 40];
  __shared__ u16 wAl[2][64 * 40];
  const int M = 256, MB = 4;
  const int xcd = blockIdx.x & 7;
  const int idx = blockIdx.x >> 3;
  const int g = xcd * 18 + idx / MB;
  const int mb = idx % MB;
  const int nb = g % 36, b = g / 36;
  const int m0 = mb * 64, n0 = nb * 64;
  const int tid = threadIdx.x;
  const int wv = tid >> 6, lane = tid & 63;
  const int wm = wv >> 1, wsd = wv & 1;
  const int lr = lane & 15, lg = lane >> 4;
  const bf16x8 zv = {0, 0, 0, 0, 0, 0, 0, 0};

  const u16* xbh = XTh + ((size_t)b * S_ + n0 + wsd * 32) * 256;
  const u16* xbl = XTl + ((size_t)b * S_ + n0 + wsd * 32) * 256;

  f32x4 acc[2][2];
#pragma unroll
  for (int mt = 0; mt < 2; mt++)
#pragma unroll
    for (int nt = 0; nt < 2; nt++) acc[mt][nt] = (f32x4){0.f, 0.f, 0.f, 0.f};

#define STAGE_W(t, buf)                                                      \
  {                                                                          \
    _Pragma("unroll")                                                        \
    for (int r = 0; r < 2; r++) {                                            \
      int id = tid + r * 256;                                                \
      int m = id >> 3, k4 = (id & 7) * 4;                                    \
      *(short4*)&wAh[buf][m * 40 + k4] =                                     \
          *(const short4*)&Wh[(size_t)(m0 + m) * 256 + (t) * 32 + k4];       \
      *(short4*)&wAl[buf][m * 40 + k4] =                                     \
          *(const short4*)&Wl[(size_t)(m0 + m) * 256 + (t) * 32 + k4];       \
    }                                                                        \
  }

  STAGE_W(0, 0);
  bf16x8 cbh[2], cbl[2];
#pragma unroll
  for (int nt = 0; nt < 2; nt++) {
    size_t off = (size_t)(nt * 16 + lr) * 256 + lg * 8;
    cbh[nt] = *(const bf16x8*)&xbh[off];
    cbl[nt] = *(const bf16x8*)&xbl[off];
  }
  __syncthreads();

  for (int t = 0; t < 8; t++) {
    int buf = t & 1;
    if (t < 7) STAGE_W(t + 1, buf ^ 1);

    bf16x8 nbh[2], nbl[2];
    if (t < 7) {
#pragma unroll
      for (int nt = 0; nt < 2; nt++) {
        size_t off = (size_t)(nt * 16 + lr) * 256 + (t + 1) * 32 + lg * 8;
        nbh[nt] = *(const bf16x8*)&xbh[off];
        nbl[nt] = *(const bf16x8*)&xbl[off];
      }
    } else {
#pragma unroll
      for (int nt = 0; nt < 2; nt++) { nbh[nt] = zv; nbl[nt] = zv; }
    }

    bf16x8 ah[2], al[2];
#pragma unroll
    for (int mt = 0; mt < 2; mt++) {
      ah[mt] = *(const bf16x8*)&wAh[buf][(wm * 32 + mt * 16 + lr) * 40 + lg * 8];
      al[mt] = *(const bf16x8*)&wAl[buf][(wm * 32 + mt * 16 + lr) * 40 + lg * 8];
    }
#pragma unroll
    for (int mt = 0; mt < 2; mt++)
#pragma unroll
      for (int nt = 0; nt < 2; nt++) {
        acc[mt][nt] = __builtin_amdgcn_mfma_f32_16x16x32_bf16(ah[mt], cbh[nt], acc[mt][nt], 0, 0, 0);
        acc[mt][nt] = __builtin_amdgcn_mfma_f32_16x16x32_bf16(ah[mt], cbl[nt], acc[mt][nt], 0, 0, 0);
        acc[mt][nt] = __builtin_amdgcn_mfma_f32_16x16x32_bf16(al[mt], cbh[nt], acc[mt][nt], 0, 0, 0);
      }
    __syncthreads();
#pragma unroll
    for (int nt = 0; nt < 2; nt++) { cbh[nt] = nbh[nt]; cbl[nt] = nbl[nt]; }
  }

  float* ob = Out + (size_t)b * M * S_;
#pragma unroll
  for (int mt = 0; mt < 2; mt++) {
    float4 b4 = *(const float4*)&bias[m0 + wm * 32 + mt * 16 + lg * 4];
    float bv[4] = {b4.x, b4.y, b4.z, b4.w};
#pragma unroll
    for (int nt = 0; nt < 2; nt++) {
      int s = n0 + wsd * 32 + nt * 16 + lr;
#pragma unroll
      for (int r = 0; r < 4; r++) {
        int m = m0 + wm * 32 + mt * 16 + lg * 4 + r;
        ob[(size_t)m * S_ + s] = acc[mt][nt][r] + bv[r];
      }
    }
  }
#undef STAGE_W
}

// ---------------------------------------------------------------------------
// Scores: blocks 0..255 = ROW attention (register-resident rq: each thread
// holds its 9 (i,w) positions' 16 d-values packed bf16 in 72 VGPRs, reused
// across 6 h -> LDS ~13 KB, 4 blocks/CU vs old 74 KB @ 1 block/CU);
// blocks 256..511 = COL attention (r12 body). Both write fragment-major bf16.
// ---------------------------------------------------------------------------
__global__ __launch_bounds__(256) void scores_kernel(
    const float* __restrict__ rcv, u16* __restrict__ arF, u16* __restrict__ awF)
{
  __shared__ float Sm[48 * 49];          // 9408 B (shared by both branches)
  __shared__ float red0[48], red1[48];
  __shared__ unsigned rkp[8 * 48];       // row: packed rk pairs  (1536 B)
  __shared__ float cq[16 * 48], ck[16 * 48];  // col: 6144 B
  const int bid = blockIdx.x;
  const int tid = threadIdx.x;

  if (bid < 256) {
    // ---------------- ROW ----------------
    const int hg = bid & 7, n = (bid >> 3) & 7, b = bid >> 6;
    const float* base = rcv + ((size_t)b * 768 + n * 96) * S_;   // rq; rk at +16*S_
    unsigned rqp[9][8];                  // [pos][d-pair] packed bf16
#pragma unroll
    for (int k = 0; k < 9; k++) {
      int p = tid + k * 256;
#pragma unroll
      for (int d8 = 0; d8 < 8; d8++) {
        float v0 = base[(size_t)(2 * d8) * S_ + p];
        float v1 = base[(size_t)(2 * d8 + 1) * S_ + p];
        rqp[k][d8] = (unsigned)f2bf(v0) | ((unsigned)f2bf(v1) << 16);
      }
    }
    for (int hh = 0; hh < 6; hh++) {
      int h = hg * 6 + hh;
      for (int id = tid; id < 384; id += 256) {
        int d8 = id / 48, w = id % 48;
        float v0 = base[(size_t)(16 + 2 * d8) * S_ + h * 48 + w];
        float v1 = base[(size_t)(16 + 2 * d8 + 1) * S_ + h * 48 + w];
        rkp[id] = (unsigned)f2bf(v0) | ((unsigned)f2bf(v1) << 16);
      }
      __syncthreads();
#pragma unroll
      for (int k = 0; k < 9; k++) {
        int p = tid + k * 256;
        int i = p / 48, w = p % 48;
        float s = 0.f;
#pragma unroll
        for (int d8 = 0; d8 < 8; d8++) {
          unsigned a = rqp[k][d8], c = rkp[d8 * 48 + w];
          s += bflo(a) * bflo(c) + bfhi(a) * bfhi(c);
        }
        Sm[i * 49 + w] = s * 0.25f;
      }
      __syncthreads();
      if (tid < 192) {
        int w = tid >> 2, e = tid & 3;
        float m = -1e30f;
        for (int i = e; i < 48; i += 4) m = fmaxf(m, Sm[i * 49 + w]);
        m = fmaxf(m, __shfl_xor(m, 1));
        m = fmaxf(m, __shfl_xor(m, 2));
        float s = 0.f;
        for (int i = e; i < 48; i += 4) s += __expf(Sm[i * 49 + w] - m);
        s += __shfl_xor(s, 1);
        s += __shfl_xor(s, 2);
        red0[w] = m; red1[w] = 1.0f / s;
      }
      __syncthreads();
      u16* dst = arF + ((size_t)(b * 8 + n) * 48 + h) * 2304;
      for (int id = tid; id < 576; id += 256) {
        int nt = id / 192, rem = id % 192, mt = rem / 64, l = rem % 64;
        int w = nt * 16 + (l & 15);
        int i0 = mt * 16 + ((l >> 4) << 2);
        short4 o;
        o.x = (short)f2bf(__expf(Sm[(i0 + 0) * 49 + w] - red0[w]) * red1[w]);
        o.y = (short)f2bf(__expf(Sm[(i0 + 1) * 49 + w] - red0[w]) * red1[w]);
        o.z = (short)f2bf(__expf(Sm[(i0 + 2) * 49 + w] - red0[w]) * red1[w]);
        o.w = (short)f2bf(__expf(Sm[(i0 + 3) * 49 + w] - red0[w]) * red1[w]);
        *(short4*)&dst[id * 4] = o;
      }
      __syncthreads();
    }
  } else {
    // ---------------- COL ----------------
    const int bid2 = bid - 256;
    const int hg = bid2 & 7, n = (bid2 >> 3) & 7, b = bid2 >> 6;
    const float* base = rcv + ((size_t)b * 768 + n * 96 + 32) * S_;  // cq; ck +16*S_
    for (int hh = 0; hh < 6; hh++) {
      int h = hg * 6 + hh;
      for (int id = tid; id < 768; id += 256) {
        int d = id / 48, j = id % 48;
        cq[id] = base[(size_t)d * S_ + h * 48 + j];
        ck[id] = base[(size_t)(16 + d) * S_ + h * 48 + j];
      }
      __syncthreads();
      for (int id = tid; id < 2304; id += 256) {
        int w = id / 48, j = id % 48;
        float t = 0.f;
#pragma unroll
        for (int d = 0; d < 16; d++)
          t += ck[d * 48 + w] * cq[d * 48 + j];
        Sm[w * 49 + j] = t * 0.25f;
      }
      __syncthreads();
      if (tid < 192) {
        int w = tid >> 2, e = tid & 3;
        float m = -1e30f;
        for (int j = e; j < 48; j += 4) m = fmaxf(m, Sm[w * 49 + j]);
        m = fmaxf(m, __shfl_xor(m, 1));
        m = fmaxf(m, __shfl_xor(m, 2));
        float s = 0.f;
        for (int j = e; j < 48; j += 4) s += __expf(Sm[w * 49 + j] - m);
        s += __shfl_xor(s, 1);
        s += __shfl_xor(s, 2);
        red0[w] = m; red1[w] = 1.0f / s;
      }
      __syncthreads();
      u16* dst = awF + ((size_t)(b * 8 + n) * 48 + h) * 3072;
      for (int id = tid; id < 384; id += 256) {
        int nt = id / 128, rem = id % 128, ks = rem / 64, l = rem % 64;
        int w = nt * 16 + (l & 15);
        int j0 = ks * 32 + ((l >> 4) << 3);
        u16 t8[8];
#pragma unroll
        for (int e = 0; e < 8; e++) {
          int j = j0 + e;
          t8[e] = (j < 48) ? f2bf(__expf(Sm[w * 49 + j] - red0[w]) * red1[w]) : (u16)0;
        }
        short4 o0, o1;
        o0.x = (short)t8[0]; o0.y = (short)t8[1]; o0.z = (short)t8[2]; o0.w = (short)t8[3];
        o1.x = (short)t8[4]; o1.y = (short)t8[5]; o1.z = (short)t8[6]; o1.w = (short)t8[7];
        *(short4*)&dst[id * 8]     = o0;
        *(short4*)&dst[id * 8 + 4] = o1;
      }
      __syncthreads();
    }
  }
}

// ---------------------------------------------------------------------------
// Main contraction + PE conv (r10 geometry + bf16 arF, verbatim r10 body).
// ---------------------------------------------------------------------------
__global__ __launch_bounds__(256) void attn_main_kernel(
    const float* __restrict__ rcv, const u16* __restrict__ arF,
    const u16* __restrict__ awF, const float* __restrict__ pe_w,
    const float* __restrict__ pe_b, float* __restrict__ y)
{
  __shared__ u16 vA[96 * 72];         // 13824 B
  const int id0 = blockIdx.x;
  const int n = id0 & 7;              // XCD swizzle
  const int rest = id0 >> 3;          // 0..255
  const int b = rest >> 6;
  const int inner = rest & 63;
  const int dchunk = inner >> 2;      // 0..15 (2 planes each)
  const int hc = inner & 3;
  const int tid = threadIdx.x;
  const int wave = tid >> 6, lane = tid & 63;
  const int dl = wave >> 1, half = wave & 1;
  const int h0 = hc * 12 + half * 6;
  const int lr = lane & 15, lg = lane >> 4;

  for (int id = tid; id < 96 * 24; id += 256) {
    int row = id / 24, col = 48 + id % 24;
    vA[row * 72 + col] = 0;
  }
  const float* vbase = rcv + ((size_t)b * 768 + n * 96 + 64 + dchunk * 2) * S_;
  for (int id = tid; id < 1152; id += 256) {
    int dl2 = id / 576, rem = id % 576;
    int i = rem / 12, j4 = (rem % 12) * 4;
    float4 v = *(const float4*)&vbase[(size_t)dl2 * S_ + i * 48 + j4];
    short4 s;
    s.x = (short)f2bf(v.x); s.y = (short)f2bf(v.y);
    s.z = (short)f2bf(v.z); s.w = (short)f2bf(v.w);
    *(short4*)&vA[(dl2 * 48 + i) * 72 + j4] = s;
  }
  __syncthreads();   // the only barrier

  const size_t bn48 = (size_t)(b * 8 + n) * 48;
  const int c = n * 32 + dchunk * 2 + dl;
  float pw[9];
#pragma unroll
  for (int t = 0; t < 9; t++) pw[t] = pe_w[c * 9 + t];
  const float pb = pe_b[c];
  float* yg = y + ((size_t)b * 256 + c) * S_;
  const int vrow0 = dl * 48;

  for (int hh = 0; hh < 6; hh++) {
    int h = h0 + hh;
    const u16* awg = awF + (bn48 + h) * 3072;
    const u16* arg = arF + (bn48 + h) * 2304;

    bf16x8 bf0[3], bf1[3];
#pragma unroll
    for (int nt = 0; nt < 3; nt++) {
      bf0[nt] = *(const bf16x8*)&awg[nt * 1024 + lane * 8];
      bf1[nt] = *(const bf16x8*)&awg[nt * 1024 + 512 + lane * 8];
    }

    f32x4 acc[3][3];
#pragma unroll
    for (int mt = 0; mt < 3; mt++)
#pragma unroll
      for (int nt = 0; nt < 3; nt++) acc[mt][nt] = (f32x4){0.f, 0.f, 0.f, 0.f};

#pragma unroll
    for (int mt = 0; mt < 3; mt++) {
      bf16x8 a0 = *(const bf16x8*)&vA[(vrow0 + mt * 16 + lr) * 72 + lg * 8];
      bf16x8 a1 = *(const bf16x8*)&vA[(vrow0 + mt * 16 + lr) * 72 + 32 + lg * 8];
#pragma unroll
      for (int nt = 0; nt < 3; nt++) {
        acc[mt][nt] = __builtin_amdgcn_mfma_f32_16x16x32_bf16(a0, bf0[nt], acc[mt][nt], 0, 0, 0);
        acc[mt][nt] = __builtin_amdgcn_mfma_f32_16x16x32_bf16(a1, bf1[nt], acc[mt][nt], 0, 0, 0);
      }
    }

    float pv[3];
#pragma unroll
    for (int nt = 0; nt < 3; nt++) {
      float p = 0.f;
#pragma unroll
      for (int mt = 0; mt < 3; mt++) {
        short4 s = *(const short4*)&arg[(nt * 3 + mt) * 256 + lane * 4];
        p += bf2f((u16)s.x) * acc[mt][nt][0] + bf2f((u16)s.y) * acc[mt][nt][1]
           + bf2f((u16)s.z) * acc[mt][nt][2] + bf2f((u16)s.w) * acc[mt][nt][3];
      }
      p += __shfl_xor(p, 16);
      p += __shfl_xor(p, 32);
      pv[nt] = p;
    }

    if (lane < 48) {
      float a = (lane < 16) ? pv[0] : (lane < 32 ? pv[1] : pv[2]);
      a += pb;
      int ww = lane;
#pragma unroll
      for (int kh = -1; kh <= 1; kh++) {
        int ih = h + kh;
        if (ih < 0 || ih > 47) continue;
#pragma unroll
        for (int kw = -1; kw <= 1; kw++) {
          int jw = ww + kw;
          if (jw < 0 || jw > 47) continue;
          a += pw[(kh + 1) * 3 + (kw + 1)] * bf2f(vA[(vrow0 + ih) * 72 + jw]);
        }
      }
      yg[h * 48 + ww] = a;
    }
  }
}

// ---------------------------------------------------------------------------
extern "C" void kernel_launch(void* const* d_in, const int* in_sizes, int n_in,
                              void* d_out, int out_size, void* d_ws, size_t ws_size,
                              hipStream_t stream) {
  const float* x      = (const float*)d_in[0];
  const float* rcv_w  = (const float*)d_in[1];
  const float* rcv_b  = (const float*)d_in[2];
  const float* pe_w   = (const float*)d_in[3];
  const float* pe_b   = (const float*)d_in[4];
  const float* proj_w = (const float*)d_in[5];
  const float* proj_b = (const float*)d_in[6];
  float* out = (float*)d_out;

  char* ws = (char*)d_ws;
  float* rcv = (float*)ws;                         // 0           28,311,552 B
  u16*   arF = (u16*)(ws + 28311552);              // 7,077,888 B
  u16*   awF = (u16*)(ws + 35389440);              // 9,437,184 B
  u16*   xTh = (u16*)(ws + 44826624);              // 4,718,592 B
  float* y   = (float*)(ws + 49545216);            // 9,437,184 B
  u16*   Whr = (u16*)(ws + 58982400);              //   393,216 B
  u16*   Wlr = (u16*)(ws + 59375616);              //   393,216 B
  u16*   Whp = (u16*)(ws + 59768832);              //   131,072 B
  u16*   Wlp = (u16*)(ws + 59899904);              //   131,072 B (end ~60 MB)
  // yT aliases arF/awF (free after attn_main)
  u16*   yTh = arF;
  u16*   yTl = awF;

  prep_kernel<<<dim3(832), 256, 0, stream>>>(rcv_w, Whr, Wlr, proj_w, Whp, Wlp, x, xTh);
  gemm_mfma_kernel<false><<<dim3(72 * 12), 256, 0, stream>>>(Whr, Wlr, rcv_b, xTh, xTh, rcv, 768);
  scores_kernel<<<dim3(512), 256, 0, stream>>>(rcv, arF, awF);
  attn_main_kernel<<<dim3(2048), 256, 0, stream>>>(rcv, arF, awF, pe_w, pe_b, y);
  split_transpose_kernel<<<dim3(36, 4, 4), 256, 0, stream>>>(y, yTh, yTl);
  gemm_n64_kernel<<<dim3(576), 256, 0, stream>>>(Whp, Wlp, proj_b, yTh, yTl, out);
}

// Round 14
// 120.282 us; speedup vs baseline: 1.7368x; 1.0104x over previous
//
#include <hip/hip_runtime.h>

#define S_ 2304   // 48*48

typedef unsigned short u16;
typedef __attribute__((ext_vector_type(8))) short bf16x8;
typedef __attribute__((ext_vector_type(4))) float f32x4;

static __device__ __forceinline__ u16 f2bf(float x) {
  union { float f; unsigned u; } v; v.f = x;
  unsigned r = v.u + 0x7FFFu + ((v.u >> 16) & 1u);
  return (u16)(r >> 16);
}
static __device__ __forceinline__ float bf2f(u16 h) {
  union { unsigned u; float f; } v; v.u = ((unsigned)h) << 16; return v.f;
}
static __device__ __forceinline__ float bflo(unsigned p) {
  union { unsigned u; float f; } v; v.u = p << 16; return v.f;
}
static __device__ __forceinline__ float bfhi(unsigned p) {
  union { unsigned u; float f; } v; v.u = p & 0xFFFF0000u; return v.f;
}

// ---------------------------------------------------------------------------
// Prep: weight split (blocks 0..255) + x split-transpose h-only (256..831).
// ---------------------------------------------------------------------------
__global__ __launch_bounds__(256) void prep_kernel(
    const float* __restrict__ w0, u16* __restrict__ wh0, u16* __restrict__ wl0,
    const float* __restrict__ w1, u16* __restrict__ wh1, u16* __restrict__ wl1,
    const float* __restrict__ x, u16* __restrict__ xTh)
{
  __shared__ u16 tile[64][65];
  const int bid = blockIdx.x;
  const int tid = threadIdx.x;
  if (bid < 256) {
    const float* w; u16 *wh, *wl; int id;
    if (bid < 192) { w = w0; wh = wh0; wl = wl0; id = bid * 256 + tid; }
    else { w = w1; wh = wh1; wl = wl1; id = (bid - 192) * 256 + tid; }
    float4 v = ((const float4*)w)[id];
    short4 h, l;
    float f[4] = {v.x, v.y, v.z, v.w};
    u16 hh[4], ll[4];
#pragma unroll
    for (int q = 0; q < 4; q++) {
      hh[q] = f2bf(f[q]);
      ll[q] = f2bf(f[q] - bf2f(hh[q]));
    }
    h.x = hh[0]; h.y = hh[1]; h.z = hh[2]; h.w = hh[3];
    l.x = ll[0]; l.y = ll[1]; l.z = ll[2]; l.w = ll[3];
    ((short4*)wh)[id] = h;
    ((short4*)wl)[id] = l;
    return;
  }
  const int bid2 = bid - 256;
  const int s0 = (bid2 % 36) * 64, c0 = ((bid2 / 36) % 4) * 64, b = bid2 / 144;
  const float* inb = x + (size_t)b * 256 * S_;
  u16* oh = xTh + (size_t)b * S_ * 256;
#pragma unroll
  for (int it = 0; it < 4; it++) {
    int id = tid + it * 256;
    int c = id >> 4, s4 = (id & 15) * 4;
    float4 v = *(const float4*)&inb[(size_t)(c0 + c) * S_ + s0 + s4];
    tile[s4 + 0][c] = f2bf(v.x);
    tile[s4 + 1][c] = f2bf(v.y);
    tile[s4 + 2][c] = f2bf(v.z);
    tile[s4 + 3][c] = f2bf(v.w);
  }
  __syncthreads();
#pragma unroll
  for (int it = 0; it < 4; it++) {
    int id = tid + it * 256;
    int s = id >> 4, c4 = (id & 15) * 4;
    short4 h;
    h.x = (short)tile[s][c4 + 0]; h.y = (short)tile[s][c4 + 1];
    h.z = (short)tile[s][c4 + 2]; h.w = (short)tile[s][c4 + 3];
    *(short4*)&oh[(size_t)(s0 + s) * 256 + c0 + c4] = h;
  }
}

// ---------------------------------------------------------------------------
// Split-transpose (h+l) for y before proj. Grid (36,4,4).
// ---------------------------------------------------------------------------
__global__ __launch_bounds__(256) void split_transpose_kernel(
    const float* __restrict__ in, u16* __restrict__ outh, u16* __restrict__ outl)
{
  __shared__ unsigned tile[64][65];
  const int s0 = blockIdx.x * 64, c0 = blockIdx.y * 64, b = blockIdx.z;
  const float* inb = in + (size_t)b * 256 * S_;
  u16* oh = outh + (size_t)b * S_ * 256;
  u16* ol = outl + (size_t)b * S_ * 256;
  const int tid = threadIdx.x;
#pragma unroll
  for (int it = 0; it < 4; it++) {
    int id = tid + it * 256;
    int c = id >> 4, s4 = (id & 15) * 4;
    float4 v = *(const float4*)&inb[(size_t)(c0 + c) * S_ + s0 + s4];
    float f[4] = {v.x, v.y, v.z, v.w};
#pragma unroll
    for (int q = 0; q < 4; q++) {
      u16 h = f2bf(f[q]);
      u16 l = f2bf(f[q] - bf2f(h));
      tile[s4 + q][c] = (unsigned)h | ((unsigned)l << 16);
    }
  }
  __syncthreads();
#pragma unroll
  for (int it = 0; it < 4; it++) {
    int id = tid + it * 256;
    int s = id >> 4, c4 = (id & 15) * 4;
    short4 h, l;
    unsigned p0 = tile[s][c4 + 0], p1 = tile[s][c4 + 1];
    unsigned p2 = tile[s][c4 + 2], p3 = tile[s][c4 + 3];
    h.x = (short)(p0 & 0xffff); h.y = (short)(p1 & 0xffff);
    h.z = (short)(p2 & 0xffff); h.w = (short)(p3 & 0xffff);
    l.x = (short)(p0 >> 16); l.y = (short)(p1 >> 16);
    l.z = (short)(p2 >> 16); l.w = (short)(p3 >> 16);
    *(short4*)&oh[(size_t)(s0 + s) * 256 + c0 + c4] = h;
    *(short4*)&ol[(size_t)(s0 + s) * 256 + c0 + c4] = l;
  }
}

// ---------------------------------------------------------------------------
// MFMA split-bf16 GEMM (r10 form), XLO=false: Out=(Wh+Wl)*Xh. BM=64 BN=128.
// ---------------------------------------------------------------------------
template <bool XLO>
__global__ __launch_bounds__(256) void gemm_mfma_kernel(
    const u16* __restrict__ Wh, const u16* __restrict__ Wl,
    const float* __restrict__ bias,
    const u16* __restrict__ XTh, const u16* __restrict__ XTl,
    float* __restrict__ Out, int M)
{
  __shared__ u16 wAh[2][64 * 40];
  __shared__ u16 wAl[2][64 * 40];
  const int MB = M >> 6;
  const int xcd = blockIdx.x & 7;
  const int idx = blockIdx.x >> 3;
  const int g = xcd * 9 + idx / MB;
  const int mb = idx % MB;
  const int nb = g % 18, b = g / 18;
  const int m0 = mb * 64, n0 = nb * 128;
  const int tid = threadIdx.x;
  const int wv = tid >> 6, lane = tid & 63;
  const int lr = lane & 15, lg = lane >> 4;
  const bf16x8 zv = {0, 0, 0, 0, 0, 0, 0, 0};

  const u16* xbh = XTh + ((size_t)b * S_ + n0 + wv * 32) * 256;
  const u16* xbl = XTl + ((size_t)b * S_ + n0 + wv * 32) * 256;

  f32x4 acc[4][2];
#pragma unroll
  for (int mt = 0; mt < 4; mt++)
#pragma unroll
    for (int nt = 0; nt < 2; nt++) acc[mt][nt] = (f32x4){0.f, 0.f, 0.f, 0.f};

#define STAGE_W(t, buf)                                                      \
  {                                                                          \
    _Pragma("unroll")                                                        \
    for (int r = 0; r < 2; r++) {                                            \
      int id = tid + r * 256;                                                \
      int m = id >> 3, k4 = (id & 7) * 4;                                    \
      *(short4*)&wAh[buf][m * 40 + k4] =                                     \
          *(const short4*)&Wh[(size_t)(m0 + m) * 256 + (t) * 32 + k4];       \
      *(short4*)&wAl[buf][m * 40 + k4] =                                     \
          *(const short4*)&Wl[(size_t)(m0 + m) * 256 + (t) * 32 + k4];       \
    }                                                                        \
  }

  STAGE_W(0, 0);
  bf16x8 cbh[2], cbl[2];
#pragma unroll
  for (int nt = 0; nt < 2; nt++) {
    size_t off = (size_t)(nt * 16 + lr) * 256 + lg * 8;
    cbh[nt] = *(const bf16x8*)&xbh[off];
    if (XLO) cbl[nt] = *(const bf16x8*)&xbl[off];
  }
  __syncthreads();

  for (int t = 0; t < 8; t++) {
    int buf = t & 1;
    if (t < 7) STAGE_W(t + 1, buf ^ 1);

    bf16x8 nbh[2], nbl[2];
    if (t < 7) {
#pragma unroll
      for (int nt = 0; nt < 2; nt++) {
        size_t off = (size_t)(nt * 16 + lr) * 256 + (t + 1) * 32 + lg * 8;
        nbh[nt] = *(const bf16x8*)&xbh[off];
        if (XLO) nbl[nt] = *(const bf16x8*)&xbl[off];
      }
    } else {
#pragma unroll
      for (int nt = 0; nt < 2; nt++) { nbh[nt] = zv; if (XLO) nbl[nt] = zv; }
    }

    bf16x8 ah[4], al[4];
#pragma unroll
    for (int mt = 0; mt < 4; mt++) {
      ah[mt] = *(const bf16x8*)&wAh[buf][(mt * 16 + lr) * 40 + lg * 8];
      al[mt] = *(const bf16x8*)&wAl[buf][(mt * 16 + lr) * 40 + lg * 8];
    }
#pragma unroll
    for (int mt = 0; mt < 4; mt++)
#pragma unroll
      for (int nt = 0; nt < 2; nt++) {
        acc[mt][nt] = __builtin_amdgcn_mfma_f32_16x16x32_bf16(ah[mt], cbh[nt], acc[mt][nt], 0, 0, 0);
        if (XLO)
          acc[mt][nt] = __builtin_amdgcn_mfma_f32_16x16x32_bf16(ah[mt], cbl[nt], acc[mt][nt], 0, 0, 0);
        acc[mt][nt] = __builtin_amdgcn_mfma_f32_16x16x32_bf16(al[mt], cbh[nt], acc[mt][nt], 0, 0, 0);
      }
    __syncthreads();
#pragma unroll
    for (int nt = 0; nt < 2; nt++) { cbh[nt] = nbh[nt]; if (XLO) cbl[nt] = nbl[nt]; }
  }

  float* ob = Out + (size_t)b * M * S_;
#pragma unroll
  for (int mt = 0; mt < 4; mt++) {
    float4 b4 = *(const float4*)&bias[m0 + mt * 16 + lg * 4];
    float bv[4] = {b4.x, b4.y, b4.z, b4.w};
#pragma unroll
    for (int nt = 0; nt < 2; nt++) {
      int s = n0 + wv * 32 + nt * 16 + lr;
#pragma unroll
      for (int r = 0; r < 4; r++) {
        int m = m0 + mt * 16 + lg * 4 + r;
        ob[(size_t)m * S_ + s] = acc[mt][nt][r] + bv[r];
      }
    }
  }
#undef STAGE_W
}

// ---------------------------------------------------------------------------
// Proj GEMM, BN=64 (576 blocks for occupancy). 3-term.
// ---------------------------------------------------------------------------
__global__ __launch_bounds__(256) void gemm_n64_kernel(
    const u16* __restrict__ Wh, const u16* __restrict__ Wl,
    const float* __restrict__ bias,
    const u16* __restrict__ XTh, const u16* __restrict__ XTl,
    float* __restrict__ Out)
{
  __shared__ u16 wAh[2][64 * 40];
  __shared__ u16 wAl[2][64 * 40];
  const int M = 256, MB = 4;
  const int xcd = blockIdx.x & 7;
  const int idx = blockIdx.x >> 3;
  const int g = xcd * 18 + idx / MB;
  const int mb = idx % MB;
  const int nb = g % 36, b = g / 36;
  const int m0 = mb * 64, n0 = nb * 64;
  const int tid = threadIdx.x;
  const int wv = tid >> 6, lane = tid & 63;
  const int wm = wv >> 1, wsd = wv & 1;
  const int lr = lane & 15, lg = lane >> 4;
  const bf16x8 zv = {0, 0, 0, 0, 0, 0, 0, 0};

  const u16* xbh = XTh + ((size_t)b * S_ + n0 + wsd * 32) * 256;
  const u16* xbl = XTl + ((size_t)b * S_ + n0 + wsd * 32) * 256;

  f32x4 acc[2][2];
#pragma unroll
  for (int mt = 0; mt < 2; mt++)
#pragma unroll
    for (int nt = 0; nt < 2; nt++) acc[mt][nt] = (f32x4){0.f, 0.f, 0.f, 0.f};

#define STAGE_W(t, buf)                                                      \
  {                                                                          \
    _Pragma("unroll")                                                        \
    for (int r = 0; r < 2; r++) {                                            \
      int id = tid + r * 256;                                                \
      int m = id >> 3, k4 = (id & 7) * 4;                                    \
      *(short4*)&wAh[buf][m * 40 + k4] =                                     \
          *(const short4*)&Wh[(size_t)(m0 + m) * 256 + (t) * 32 + k4];       \
      *(short4*)&wAl[buf][m * 40 + k4] =                                     \
          *(const short4*)&Wl[(size_t)(m0 + m) * 256 + (t) * 32 + k4];       \
    }                                                                        \
  }

  STAGE_W(0, 0);
  bf16x8 cbh[2], cbl[2];
#pragma unroll
  for (int nt = 0; nt < 2; nt++) {
    size_t off = (size_t)(nt * 16 + lr) * 256 + lg * 8;
    cbh[nt] = *(const bf16x8*)&xbh[off];
    cbl[nt] = *(const bf16x8*)&xbl[off];
  }
  __syncthreads();

  for (int t = 0; t < 8; t++) {
    int buf = t & 1;
    if (t < 7) STAGE_W(t + 1, buf ^ 1);

    bf16x8 nbh[2], nbl[2];
    if (t < 7) {
#pragma unroll
      for (int nt = 0; nt < 2; nt++) {
        size_t off = (size_t)(nt * 16 + lr) * 256 + (t + 1) * 32 + lg * 8;
        nbh[nt] = *(const bf16x8*)&xbh[off];
        nbl[nt] = *(const bf16x8*)&xbl[off];
      }
    } else {
#pragma unroll
      for (int nt = 0; nt < 2; nt++) { nbh[nt] = zv; nbl[nt] = zv; }
    }

    bf16x8 ah[2], al[2];
#pragma unroll
    for (int mt = 0; mt < 2; mt++) {
      ah[mt] = *(const bf16x8*)&wAh[buf][(wm * 32 + mt * 16 + lr) * 40 + lg * 8];
      al[mt] = *(const bf16x8*)&wAl[buf][(wm * 32 + mt * 16 + lr) * 40 + lg * 8];
    }
#pragma unroll
    for (int mt = 0; mt < 2; mt++)
#pragma unroll
      for (int nt = 0; nt < 2; nt++) {
        acc[mt][nt] = __builtin_amdgcn_mfma_f32_16x16x32_bf16(ah[mt], cbh[nt], acc[mt][nt], 0, 0, 0);
        acc[mt][nt] = __builtin_amdgcn_mfma_f32_16x16x32_bf16(ah[mt], cbl[nt], acc[mt][nt], 0, 0, 0);
        acc[mt][nt] = __builtin_amdgcn_mfma_f32_16x16x32_bf16(al[mt], cbh[nt], acc[mt][nt], 0, 0, 0);
      }
    __syncthreads();
#pragma unroll
    for (int nt = 0; nt < 2; nt++) { cbh[nt] = nbh[nt]; cbl[nt] = nbl[nt]; }
  }

  float* ob = Out + (size_t)b * M * S_;
#pragma unroll
  for (int mt = 0; mt < 2; mt++) {
    float4 b4 = *(const float4*)&bias[m0 + wm * 32 + mt * 16 + lg * 4];
    float bv[4] = {b4.x, b4.y, b4.z, b4.w};
#pragma unroll
    for (int nt = 0; nt < 2; nt++) {
      int s = n0 + wsd * 32 + nt * 16 + lr;
#pragma unroll
      for (int r = 0; r < 4; r++) {
        int m = m0 + wm * 32 + mt * 16 + lg * 4 + r;
        ob[(size_t)m * S_ + s] = acc[mt][nt][r] + bv[r];
      }
    }
  }
#undef STAGE_W
}

// ---------------------------------------------------------------------------
// Scores: r13 bodies, but h-groups split 8->16 (3 h per block) so the grid
// doubles to 1024 blocks = 4 blocks/CU = 16 waves/CU (was 2 blocks/CU,
// OccupancyPercent 16.8 -> grid-starved latency). rq preload re-read cost
// (x2, L2-cached) is the price for 2x latency overlap.
// blocks 0..511 = ROW, 512..1023 = COL.
// ---------------------------------------------------------------------------
__global__ __launch_bounds__(256) void scores_kernel(
    const float* __restrict__ rcv, u16* __restrict__ arF, u16* __restrict__ awF)
{
  __shared__ float Sm[48 * 49];
  __shared__ float red0[48], red1[48];
  __shared__ unsigned rkp[8 * 48];
  __shared__ float cq[16 * 48], ck[16 * 48];
  const int bid = blockIdx.x;
  const int tid = threadIdx.x;

  if (bid < 512) {
    // ---------------- ROW ----------------
    const int hg = bid & 15, n = (bid >> 4) & 7, b = bid >> 7;
    const float* base = rcv + ((size_t)b * 768 + n * 96) * S_;   // rq; rk at +16*S_
    unsigned rqp[9][8];
#pragma unroll
    for (int k = 0; k < 9; k++) {
      int p = tid + k * 256;
#pragma unroll
      for (int d8 = 0; d8 < 8; d8++) {
        float v0 = base[(size_t)(2 * d8) * S_ + p];
        float v1 = base[(size_t)(2 * d8 + 1) * S_ + p];
        rqp[k][d8] = (unsigned)f2bf(v0) | ((unsigned)f2bf(v1) << 16);
      }
    }
    for (int hh = 0; hh < 3; hh++) {
      int h = hg * 3 + hh;
      for (int id = tid; id < 384; id += 256) {
        int d8 = id / 48, w = id % 48;
        float v0 = base[(size_t)(16 + 2 * d8) * S_ + h * 48 + w];
        float v1 = base[(size_t)(16 + 2 * d8 + 1) * S_ + h * 48 + w];
        rkp[id] = (unsigned)f2bf(v0) | ((unsigned)f2bf(v1) << 16);
      }
      __syncthreads();
#pragma unroll
      for (int k = 0; k < 9; k++) {
        int p = tid + k * 256;
        int i = p / 48, w = p % 48;
        float s = 0.f;
#pragma unroll
        for (int d8 = 0; d8 < 8; d8++) {
          unsigned a = rqp[k][d8], c = rkp[d8 * 48 + w];
          s += bflo(a) * bflo(c) + bfhi(a) * bfhi(c);
        }
        Sm[i * 49 + w] = s * 0.25f;
      }
      __syncthreads();
      if (tid < 192) {
        int w = tid >> 2, e = tid & 3;
        float m = -1e30f;
        for (int i = e; i < 48; i += 4) m = fmaxf(m, Sm[i * 49 + w]);
        m = fmaxf(m, __shfl_xor(m, 1));
        m = fmaxf(m, __shfl_xor(m, 2));
        float s = 0.f;
        for (int i = e; i < 48; i += 4) s += __expf(Sm[i * 49 + w] - m);
        s += __shfl_xor(s, 1);
        s += __shfl_xor(s, 2);
        red0[w] = m; red1[w] = 1.0f / s;
      }
      __syncthreads();
      u16* dst = arF + ((size_t)(b * 8 + n) * 48 + h) * 2304;
      for (int id = tid; id < 576; id += 256) {
        int nt = id / 192, rem = id % 192, mt = rem / 64, l = rem % 64;
        int w = nt * 16 + (l & 15);
        int i0 = mt * 16 + ((l >> 4) << 2);
        short4 o;
        o.x = (short)f2bf(__expf(Sm[(i0 + 0) * 49 + w] - red0[w]) * red1[w]);
        o.y = (short)f2bf(__expf(Sm[(i0 + 1) * 49 + w] - red0[w]) * red1[w]);
        o.z = (short)f2bf(__expf(Sm[(i0 + 2) * 49 + w] - red0[w]) * red1[w]);
        o.w = (short)f2bf(__expf(Sm[(i0 + 3) * 49 + w] - red0[w]) * red1[w]);
        *(short4*)&dst[id * 4] = o;
      }
      __syncthreads();
    }
  } else {
    // ---------------- COL ----------------
    const int bid2 = bid - 512;
    const int hg = bid2 & 15, n = (bid2 >> 4) & 7, b = bid2 >> 7;
    const float* base = rcv + ((size_t)b * 768 + n * 96 + 32) * S_;  // cq; ck +16*S_
    for (int hh = 0; hh < 3; hh++) {
      int h = hg * 3 + hh;
      for (int id = tid; id < 768; id += 256) {
        int d = id / 48, j = id % 48;
        cq[id] = base[(size_t)d * S_ + h * 48 + j];
        ck[id] = base[(size_t)(16 + d) * S_ + h * 48 + j];
      }
      __syncthreads();
      for (int id = tid; id < 2304; id += 256) {
        int w = id / 48, j = id % 48;
        float t = 0.f;
#pragma unroll
        for (int d = 0; d < 16; d++)
          t += ck[d * 48 + w] * cq[d * 48 + j];
        Sm[w * 49 + j] = t * 0.25f;
      }
      __syncthreads();
      if (tid < 192) {
        int w = tid >> 2, e = tid & 3;
        float m = -1e30f;
        for (int j = e; j < 48; j += 4) m = fmaxf(m, Sm[w * 49 + j]);
        m = fmaxf(m, __shfl_xor(m, 1));
        m = fmaxf(m, __shfl_xor(m, 2));
        float s = 0.f;
        for (int j = e; j < 48; j += 4) s += __expf(Sm[w * 49 + j] - m);
        s += __shfl_xor(s, 1);
        s += __shfl_xor(s, 2);
        red0[w] = m; red1[w] = 1.0f / s;
      }
      __syncthreads();
      u16* dst = awF + ((size_t)(b * 8 + n) * 48 + h) * 3072;
      for (int id = tid; id < 384; id += 256) {
        int nt = id / 128, rem = id % 128, ks = rem / 64, l = rem % 64;
        int w = nt * 16 + (l & 15);
        int j0 = ks * 32 + ((l >> 4) << 3);
        u16 t8[8];
#pragma unroll
        for (int e = 0; e < 8; e++) {
          int j = j0 + e;
          t8[e] = (j < 48) ? f2bf(__expf(Sm[w * 49 + j] - red0[w]) * red1[w]) : (u16)0;
        }
        short4 o0, o1;
        o0.x = (short)t8[0]; o0.y = (short)t8[1]; o0.z = (short)t8[2]; o0.w = (short)t8[3];
        o1.x = (short)t8[4]; o1.y = (short)t8[5]; o1.z = (short)t8[6]; o1.w = (short)t8[7];
        *(short4*)&dst[id * 8]     = o0;
        *(short4*)&dst[id * 8 + 4] = o1;
      }
      __syncthreads();
    }
  }
}

// ---------------------------------------------------------------------------
// Main contraction + PE conv (r10 geometry + bf16 arF, verbatim r13 body).
// ---------------------------------------------------------------------------
__global__ __launch_bounds__(256) void attn_main_kernel(
    const float* __restrict__ rcv, const u16* __restrict__ arF,
    const u16* __restrict__ awF, const float* __restrict__ pe_w,
    const float* __restrict__ pe_b, float* __restrict__ y)
{
  __shared__ u16 vA[96 * 72];         // 13824 B
  const int id0 = blockIdx.x;
  const int n = id0 & 7;              // XCD swizzle
  const int rest = id0 >> 3;          // 0..255
  const int b = rest >> 6;
  const int inner = rest & 63;
  const int dchunk = inner >> 2;      // 0..15 (2 planes each)
  const int hc = inner & 3;
  const int tid = threadIdx.x;
  const int wave = tid >> 6, lane = tid & 63;
  const int dl = wave >> 1, half = wave & 1;
  const int h0 = hc * 12 + half * 6;
  const int lr = lane & 15, lg = lane >> 4;

  for (int id = tid; id < 96 * 24; id += 256) {
    int row = id / 24, col = 48 + id % 24;
    vA[row * 72 + col] = 0;
  }
  const float* vbase = rcv + ((size_t)b * 768 + n * 96 + 64 + dchunk * 2) * S_;
  for (int id = tid; id < 1152; id += 256) {
    int dl2 = id / 576, rem = id % 576;
    int i = rem / 12, j4 = (rem % 12) * 4;
    float4 v = *(const float4*)&vbase[(size_t)dl2 * S_ + i * 48 + j4];
    short4 s;
    s.x = (short)f2bf(v.x); s.y = (short)f2bf(v.y);
    s.z = (short)f2bf(v.z); s.w = (short)f2bf(v.w);
    *(short4*)&vA[(dl2 * 48 + i) * 72 + j4] = s;
  }
  __syncthreads();   // the only barrier

  const size_t bn48 = (size_t)(b * 8 + n) * 48;
  const int c = n * 32 + dchunk * 2 + dl;
  float pw[9];
#pragma unroll
  for (int t = 0; t < 9; t++) pw[t] = pe_w[c * 9 + t];
  const float pb = pe_b[c];
  float* yg = y + ((size_t)b * 256 + c) * S_;
  const int vrow0 = dl * 48;

  for (int hh = 0; hh < 6; hh++) {
    int h = h0 + hh;
    const u16* awg = awF + (bn48 + h) * 3072;
    const u16* arg = arF + (bn48 + h) * 2304;

    bf16x8 bf0[3], bf1[3];
#pragma unroll
    for (int nt = 0; nt < 3; nt++) {
      bf0[nt] = *(const bf16x8*)&awg[nt * 1024 + lane * 8];
      bf1[nt] = *(const bf16x8*)&awg[nt * 1024 + 512 + lane * 8];
    }

    f32x4 acc[3][3];
#pragma unroll
    for (int mt = 0; mt < 3; mt++)
#pragma unroll
      for (int nt = 0; nt < 3; nt++) acc[mt][nt] = (f32x4){0.f, 0.f, 0.f, 0.f};

#pragma unroll
    for (int mt = 0; mt < 3; mt++) {
      bf16x8 a0 = *(const bf16x8*)&vA[(vrow0 + mt * 16 + lr) * 72 + lg * 8];
      bf16x8 a1 = *(const bf16x8*)&vA[(vrow0 + mt * 16 + lr) * 72 + 32 + lg * 8];
#pragma unroll
      for (int nt = 0; nt < 3; nt++) {
        acc[mt][nt] = __builtin_amdgcn_mfma_f32_16x16x32_bf16(a0, bf0[nt], acc[mt][nt], 0, 0, 0);
        acc[mt][nt] = __builtin_amdgcn_mfma_f32_16x16x32_bf16(a1, bf1[nt], acc[mt][nt], 0, 0, 0);
      }
    }

    float pv[3];
#pragma unroll
    for (int nt = 0; nt < 3; nt++) {
      float p = 0.f;
#pragma unroll
      for (int mt = 0; mt < 3; mt++) {
        short4 s = *(const short4*)&arg[(nt * 3 + mt) * 256 + lane * 4];
        p += bf2f((u16)s.x) * acc[mt][nt][0] + bf2f((u16)s.y) * acc[mt][nt][1]
           + bf2f((u16)s.z) * acc[mt][nt][2] + bf2f((u16)s.w) * acc[mt][nt][3];
      }
      p += __shfl_xor(p, 16);
      p += __shfl_xor(p, 32);
      pv[nt] = p;
    }

    if (lane < 48) {
      float a = (lane < 16) ? pv[0] : (lane < 32 ? pv[1] : pv[2]);
      a += pb;
      int ww = lane;
#pragma unroll
      for (int kh = -1; kh <= 1; kh++) {
        int ih = h + kh;
        if (ih < 0 || ih > 47) continue;
#pragma unroll
        for (int kw = -1; kw <= 1; kw++) {
          int jw = ww + kw;
          if (jw < 0 || jw > 47) continue;
          a += pw[(kh + 1) * 3 + (kw + 1)] * bf2f(vA[(vrow0 + ih) * 72 + jw]);
        }
      }
      yg[h * 48 + ww] = a;
    }
  }
}

// ---------------------------------------------------------------------------
extern "C" void kernel_launch(void* const* d_in, const int* in_sizes, int n_in,
                              void* d_out, int out_size, void* d_ws, size_t ws_size,
                              hipStream_t stream) {
  const float* x      = (const float*)d_in[0];
  const float* rcv_w  = (const float*)d_in[1];
  const float* rcv_b  = (const float*)d_in[2];
  const float* pe_w   = (const float*)d_in[3];
  const float* pe_b   = (const float*)d_in[4];
  const float* proj_w = (const float*)d_in[5];
  const float* proj_b = (const float*)d_in[6];
  float* out = (float*)d_out;

  char* ws = (char*)d_ws;
  float* rcv = (float*)ws;                         // 0           28,311,552 B
  u16*   arF = (u16*)(ws + 28311552);              // 7,077,888 B
  u16*   awF = (u16*)(ws + 35389440);              // 9,437,184 B
  u16*   xTh = (u16*)(ws + 44826624);              // 4,718,592 B
  float* y   = (float*)(ws + 49545216);            // 9,437,184 B
  u16*   Whr = (u16*)(ws + 58982400);              //   393,216 B
  u16*   Wlr = (u16*)(ws + 59375616);              //   393,216 B
  u16*   Whp = (u16*)(ws + 59768832);              //   131,072 B
  u16*   Wlp = (u16*)(ws + 59899904);              //   131,072 B (end ~60 MB)
  // yT aliases arF/awF (free after attn_main)
  u16*   yTh = arF;
  u16*   yTl = awF;

  prep_kernel<<<dim3(832), 256, 0, stream>>>(rcv_w, Whr, Wlr, proj_w, Whp, Wlp, x, xTh);
  gemm_mfma_kernel<false><<<dim3(72 * 12), 256, 0, stream>>>(Whr, Wlr, rcv_b, xTh, xTh, rcv, 768);
  scores_kernel<<<dim3(1024), 256, 0, stream>>>(rcv, arF, awF);
  attn_main_kernel<<<dim3(2048), 256, 0, stream>>>(rcv, arF, awF, pe_w, pe_b, y);
  split_transpose_kernel<<<dim3(36, 4, 4), 256, 0, stream>>>(y, yTh, yTl);
  gemm_n64_kernel<<<dim3(576), 256, 0, stream>>>(Whp, Wlp, proj_b, yTh, yTl, out);
}